// Round 1
// baseline (314.296 us; speedup 1.0000x reference)
//
#include <hip/hip_runtime.h>
#include <hip/hip_bf16.h>
#include <cstdint>
#include <cstddef>

#define TT 1024
#define NN 64
#define CC 512
#define SS 64
#define UU (2 * SS + 1)
#define NEGF (-1e30f)

// ---------------------------------------------------------------------------
// Kernel 1: fused row pass over all (t,n) rows of log_probs.
//  - argmax over C (first-occurrence tiebreak)  -> pred[n*T + t]
//  - gather log_probs[t,n,targets[n,s]] s=0..63 -> Gt[(t*N+n)*64 + s]
//  - gather log_probs[t,n,0] (blank)            -> Gb[t*N+n]
// One wave per row, 4 waves (rows) per block.
// ---------------------------------------------------------------------------
__global__ __launch_bounds__(256) void k_rowpass(
    const float* __restrict__ lp, const int* __restrict__ targets,
    float* __restrict__ Gt, float* __restrict__ Gb, int* __restrict__ pred) {
  __shared__ float rows[4][CC];
  const int tid = threadIdx.x;
  const int wid = tid >> 6;
  const int l = tid & 63;
  const int r = blockIdx.x * 4 + wid;  // r = t*N + n
  const int t = r >> 6;                // N == 64
  const int n = r & 63;

  const float* row = lp + (size_t)r * CC;
  const float4 v0 = ((const float4*)row)[l];        // classes 4l..4l+3
  const float4 v1 = ((const float4*)row)[l + 64];   // classes 256+4l..

  ((float4*)rows[wid])[l] = v0;
  ((float4*)rows[wid])[l + 64] = v1;

  // argmax with first-index tiebreak
  float bv = v0.x;
  int bi = 4 * l;
#define UPD(v, i)                                  \
  do {                                             \
    if ((v) > bv || ((v) == bv && (i) < bi)) {     \
      bv = (v);                                    \
      bi = (i);                                    \
    }                                              \
  } while (0)
  UPD(v0.y, 4 * l + 1);
  UPD(v0.z, 4 * l + 2);
  UPD(v0.w, 4 * l + 3);
  UPD(v1.x, 256 + 4 * l);
  UPD(v1.y, 256 + 4 * l + 1);
  UPD(v1.z, 256 + 4 * l + 2);
  UPD(v1.w, 256 + 4 * l + 3);
#pragma unroll
  for (int off = 32; off; off >>= 1) {
    float ov = __shfl_xor(bv, off);
    int oi = __shfl_xor(bi, off);
    UPD(ov, oi);
  }
#undef UPD

  __syncthreads();

  const int tl = targets[n * SS + l];
  const float gv = rows[wid][tl];
  Gt[(size_t)r * 64 + l] = gv;
  if (l == 0) {
    Gb[r] = rows[wid][0];
    pred[n * TT + t] = bi;
  }
}

// ---------------------------------------------------------------------------
// log-sum-exp helpers (all inputs finite; NEG = -1e30 sentinel, no NaN paths)
// ---------------------------------------------------------------------------
__device__ __forceinline__ float laddexp2f(float x, float y) {
  float m = fmaxf(x, y);
  float d = fabsf(x - y);
  return m + __logf(1.0f + __expf(-d));
}
__device__ __forceinline__ float laddexp3f(float x, float y, float z) {
  float m = fmaxf(fmaxf(x, y), z);  // v_max3_f32
  float s = __expf(x - m) + __expf(y - m) + __expf(z - m);
  return m + __logf(s);
}

// ---------------------------------------------------------------------------
// Kernel 2: CTC alpha recursion. One wave per batch element n.
// Lane l holds states u=2l (even/blank) and u=2l+1 (odd/target l);
// lane 63 additionally holds u=128 (even/blank).
// ---------------------------------------------------------------------------
__global__ __launch_bounds__(64) void k_ctc(
    const float* __restrict__ Gt, const float* __restrict__ Gb,
    const int* __restrict__ targets, const int* __restrict__ ilen,
    const int* __restrict__ tlen, float* __restrict__ content) {
  const int n = blockIdx.x;
  const int l = threadIdx.x;

  const int tgt = targets[n * SS + l];
  const int tprev = __shfl_up(tgt, 1);
  const bool skip = (tgt != 0) && ((l == 0) || (tgt != tprev));
  const int L_in = ilen[n];
  const int L_tg = tlen[n];

  // t = 0 init
  const float lpb0 = Gb[n];
  const float gt0 = Gt[(size_t)n * 64 + l];
  float e0 = (l == 0) ? lpb0 : NEGF;
  float e1 = (l == 0) ? gt0 : NEGF;
  float e2 = NEGF;
  float s0 = e0, s1 = e1, s2 = e2;  // snapshot at t = L_in-1

  // prefetch pointers for t = 1
  const float* gp = Gt + ((size_t)(NN + n) * 64 + l);
  const float* bp = Gb + NN + n;
  float gt_n = *gp;
  float lpb_n = *bp;

  for (int t = 1; t < TT; ++t) {
    const float gt = gt_n;
    const float lpb = lpb_n;
    gp += NN * 64;
    bp += NN;
    if (t + 1 < TT) {  // uniform branch; prefetch next step
      gt_n = *gp;
      lpb_n = *bp;
    }

    float up1 = __shfl_up(e1, 1);  // a[2l-1] (old)
    if (l == 0) up1 = NEGF;

    const float n0 = laddexp2f(e0, up1) + lpb;                         // u=2l
    const float n1 = laddexp3f(e1, e0, skip ? up1 : NEGF) + gt;        // u=2l+1
    const float n2 = laddexp2f(e2, e1) + lpb;                          // u=128 (lane 63)
    e0 = n0;
    e1 = n1;
    e2 = n2;
    if (t == L_in - 1) {
      s0 = e0;
      s1 = e1;
      s2 = e2;
    }
  }

  const float vA = (L_tg < 64) ? __shfl(s0, L_tg) : __shfl(s2, 63);  // u = 2L
  const float vB = __shfl(s1, L_tg - 1);                             // u = 2L-1
  float loss = -laddexp2f(vA, vB);
  if (loss > 1e20f) loss = 0.0f;
  if (l == 0) content[n] = loss;
}

// ---------------------------------------------------------------------------
// Kernel 3: structural penalty. One wave per n.
// Compact struct targets into LDS, then stream preds in 64-wide chunks with
// ballot-based compaction and compare on the fly.
// ---------------------------------------------------------------------------
__global__ __launch_bounds__(64) void k_pen(
    const int* __restrict__ pred, const int* __restrict__ targets,
    const int* __restrict__ ilen, const int* __restrict__ tlen,
    float* __restrict__ pen) {
  __shared__ int ts[SS];
  const int n = blockIdx.x;
  const int l = threadIdx.x;

  const int tv = targets[n * SS + l];
  const bool tf = (l < tlen[n]) && (tv >= 1) && (tv <= 8);
  const unsigned long long tm = __ballot(tf);
  const int tcnt = __popcll(tm);
  if (tf) ts[__popcll(tm & ((1ull << l) - 1ull))] = tv;
  __syncthreads();

  const int L_in = ilen[n];
  int mism = 0;
  int prevc = -1;
  int base = 0;
#pragma unroll 4
  for (int c = 0; c < TT / 64; ++c) {
    const int t = c * 64 + l;
    int p = pred[n * TT + t];
    if (t >= L_in) p = 0;
    int pp = __shfl_up(p, 1);
    if (l == 0) pp = prevc;
    const bool keep = (p != pp) && (p >= 1) && (p <= 8);
    const unsigned long long m = __ballot(keep);
    const int pos = base + __popcll(m & ((1ull << l) - 1ull));
    if (keep && (pos >= tcnt || ts[pos] != p)) mism = 1;
    base += __popcll(m);
    prevc = __shfl(p, 63);
  }
  if (base != tcnt) mism = 1;
  if (__any(mism)) mism = 1;
  if (l == 0) pen[n] = mism ? 1.0f : 0.0f;
}

// ---------------------------------------------------------------------------
// Kernel 4: final mean reduction -> scalar
// ---------------------------------------------------------------------------
__global__ __launch_bounds__(64) void k_red(
    const float* __restrict__ content, const float* __restrict__ pen,
    float* __restrict__ out) {
  const int l = threadIdx.x;
  float v = content[l] + pen[l];  // STRUCT_WEIGHT = 1.0
#pragma unroll
  for (int off = 32; off; off >>= 1) v += __shfl_down(v, off);
  if (l == 0) out[0] = v * (1.0f / NN);
}

extern "C" void kernel_launch(void* const* d_in, const int* in_sizes, int n_in,
                              void* d_out, int out_size, void* d_ws,
                              size_t ws_size, hipStream_t stream) {
  const float* log_probs = (const float*)d_in[0];  // (T,N,C) f32
  const int* targets = (const int*)d_in[1];        // (N,S) i32
  const int* input_lengths = (const int*)d_in[2];  // (N,) i32
  const int* target_lengths = (const int*)d_in[3]; // (N,) i32
  float* out = (float*)d_out;

  // workspace layout
  float* Gt = (float*)d_ws;                       // T*N*64 f32 (16 MB)
  float* Gb = Gt + (size_t)TT * NN * 64;          // T*N f32 (256 KB)
  int* pred = (int*)(Gb + (size_t)TT * NN);       // N*T i32 (256 KB)
  float* content = (float*)(pred + (size_t)NN * TT);
  float* pen = content + NN;

  k_rowpass<<<TT * NN / 4, 256, 0, stream>>>(log_probs, targets, Gt, Gb, pred);
  k_ctc<<<NN, 64, 0, stream>>>(Gt, Gb, targets, input_lengths, target_lengths,
                               content);
  k_pen<<<NN, 64, 0, stream>>>(pred, targets, input_lengths, target_lengths,
                               pen);
  k_red<<<1, 64, 0, stream>>>(content, pen, out);
}

// Round 2
// 114.429 us; speedup vs baseline: 2.7466x; 2.7466x over previous
//
#include <hip/hip_runtime.h>
#include <hip/hip_bf16.h>
#include <cstdint>
#include <cstddef>

#define TT 1024
#define NN 64
#define CC 512
#define SS 64
#define NEGF (-1e30f)
#define LOG2E 1.4426950408889634f
#define LN2F 0.6931471805599453f

__device__ __forceinline__ float exp2i(float x) { return __builtin_amdgcn_exp2f(x); }
__device__ __forceinline__ float log2i(float x) { return __builtin_amdgcn_logf(x); }

// log-sum-exp in log2 domain
__device__ __forceinline__ float lse2(float x, float y) {
  float m = fmaxf(x, y);
  float d = fabsf(x - y);
  return m + log2i(1.0f + exp2i(-d));
}
__device__ __forceinline__ float lse3(float x, float y, float z) {
  float m = fmaxf(fmaxf(x, y), z);  // v_max3_f32
  float s = exp2i(x - m) + exp2i(y - m) + exp2i(z - m);
  return m + log2i(s);
}

// lane l gets lane l-1's value; lane 0 gets `oldv` (DPP wave_shr:1, bound_ctrl=0)
__device__ __forceinline__ float dpp_shr1(float x, float oldv) {
  int r = __builtin_amdgcn_update_dpp(__float_as_int(oldv), __float_as_int(x),
                                      0x138 /*wave_shr:1*/, 0xF, 0xF, false);
  return __int_as_float(r);
}

// ---------------------------------------------------------------------------
// Kernel 1: fused row pass. Block = one n × 16 consecutive t. 4 waves; each
// wave processes 4 rows (argmax + gather into LDS), then the block writes the
// gathered values TRANSPOSED: Gt2[(n*64+l)*T + t] (full 64B line per lane).
// Values are scaled by log2(e) so the CTC kernel works in log2 domain.
// ---------------------------------------------------------------------------
__global__ __launch_bounds__(256) void k_rowpass(
    const float* __restrict__ lp, const int* __restrict__ targets,
    float* __restrict__ Gt, float* __restrict__ Gb, int* __restrict__ pred) {
  __shared__ float rows[4][CC];
  __shared__ float Gs[16][65];  // [t_local][s], padded
  __shared__ float Gsb[16];     // blank per t_local
  const int tid = threadIdx.x;
  const int wid = tid >> 6;
  const int l = tid & 63;
  const int n = blockIdx.x & 63;
  const int tc = blockIdx.x >> 6;  // t-chunk of 16

  const int tgt = targets[n * SS + l];

  for (int i = 0; i < 4; ++i) {
    const int tl = wid * 4 + i;  // local t in [0,16)
    const int t = tc * 16 + tl;
    const float* row = lp + ((size_t)t * NN + n) * CC;
    const float4 v0 = ((const float4*)row)[l];
    const float4 v1 = ((const float4*)row)[l + 64];
    ((float4*)rows[wid])[l] = v0;
    ((float4*)rows[wid])[l + 64] = v1;

    // argmax with first-index tiebreak
    float bv = v0.x;
    int bi = 4 * l;
#define UPD(v, idx)                                \
    do {                                           \
      if ((v) > bv || ((v) == bv && (idx) < bi)) { \
        bv = (v);                                  \
        bi = (idx);                                \
      }                                            \
    } while (0)
    UPD(v0.y, 4 * l + 1);
    UPD(v0.z, 4 * l + 2);
    UPD(v0.w, 4 * l + 3);
    UPD(v1.x, 256 + 4 * l);
    UPD(v1.y, 256 + 4 * l + 1);
    UPD(v1.z, 256 + 4 * l + 2);
    UPD(v1.w, 256 + 4 * l + 3);
#pragma unroll
    for (int off = 32; off; off >>= 1) {
      float ov = __shfl_xor(bv, off);
      int oi = __shfl_xor(bi, off);
      UPD(ov, oi);
    }
#undef UPD

    const float gv = rows[wid][tgt];  // compiler inserts lgkm wait
    Gs[tl][l] = gv * LOG2E;
    if (l == 0) {
      Gsb[tl] = v0.x * LOG2E;  // class 0 = lane0's v0.x
      pred[n * TT + t] = bi;
    }
  }
  __syncthreads();

  // transpose write: thread (l, q) writes t = tc*16 + q*4 .. +3 for strip l
  const int q = tid >> 6;
  float4 w;
  w.x = Gs[q * 4 + 0][l];
  w.y = Gs[q * 4 + 1][l];
  w.z = Gs[q * 4 + 2][l];
  w.w = Gs[q * 4 + 3][l];
  ((float4*)(Gt + (size_t)(n * 64 + l) * TT + tc * 16))[q] = w;
  if (tid < 16) Gb[(size_t)n * TT + tc * 16 + tid] = Gsb[tid];
}

// ---------------------------------------------------------------------------
// Kernel 2: CTC alpha recursion, one wave per n, log2 domain.
// Lane l holds odd state u=2l+1 (e1) and even state u=2l+2 (e0).
// State u=0 is a uniform running sum a0 (blank-only chain).
// Cross-lane neighbor values via DPP wave_shr:1 (lane0 boundary from `old`).
// Gt strip is contiguous per lane; 8-deep float4 ring prefetch (32 steps).
// ---------------------------------------------------------------------------
__global__ __launch_bounds__(64) void k_ctc(
    const float* __restrict__ Gt, const float* __restrict__ Gb,
    const int* __restrict__ targets, const int* __restrict__ ilen,
    const int* __restrict__ tlen, float* __restrict__ content) {
  const int n = blockIdx.x;
  const int l = threadIdx.x;

  const int tgt = targets[n * SS + l];
  const int tprev = __shfl_up(tgt, 1);
  const bool skip = (l == 0) || (tgt != tprev);  // targets are >= 1 (no blank)
  const int Lm1 = __builtin_amdgcn_readfirstlane(ilen[n]) - 1;
  const int Ltg = __builtin_amdgcn_readfirstlane(tlen[n]);

  const float* bt = Gt + (size_t)(n * 64 + l) * TT;
  const float* bb = Gb + (size_t)n * TT;

  float4 ring[8], ringb[8];
#pragma unroll
  for (int i = 0; i < 8; ++i) {
    ring[i] = ((const float4*)bt)[i];
    ringb[i] = ((const float4*)bb)[i];
  }

  // virtual pre-state: applying step t=0 yields exact alpha_0
  float e0 = NEGF, e1 = NEGF, a0 = 0.0f;
  float s0 = NEGF, s1 = NEGF;

  for (int g = 0; g < 32; ++g) {
#pragma unroll
    for (int ci = 0; ci < 8; ++ci) {
      const int c = g * 8 + ci;  // chunk of 4 steps
      const float4 gt4 = ring[ci];
      const float4 gb4 = ringb[ci];
      if (c + 8 < 256) {
        ring[ci] = ((const float4*)bt)[c + 8];
        ringb[ci] = ((const float4*)bb)[c + 8];
      }
#pragma unroll
      for (int j = 0; j < 4; ++j) {
        const int t = c * 4 + j;
        const float gt = (&gt4.x)[j];   // static index (unrolled)
        const float lpb = (&gb4.x)[j];
        const float upE = dpp_shr1(e0, a0);    // alpha[2l]   (lane0 -> a0)
        const float upO = dpp_shr1(e1, NEGF);  // alpha[2l-1] (lane0 -> NEG)
        const float z = skip ? upO : NEGF;
        const float n1 = lse3(e1, upE, z) + gt;  // odd  u=2l+1
        const float n0 = lse2(e0, e1) + lpb;     // even u=2l+2
        a0 = a0 + lpb;                           // u=0 (blank-only chain)
        e0 = n0;
        e1 = n1;
        if (t == Lm1) {  // uniform (scalar) condition
          s0 = e0;
          s1 = e1;
        }
      }
    }
  }

  const float vA = __shfl(s0, Ltg - 1);  // u = 2*Ltg     (even of lane Ltg-1)
  const float vB = __shfl(s1, Ltg - 1);  // u = 2*Ltg - 1 (odd  of lane Ltg-1)
  float loss = -lse2(vA, vB) * LN2F;
  if (loss > 1e20f) loss = 0.0f;
  if (l == 0) content[n] = loss;
}

// ---------------------------------------------------------------------------
// Kernel 3: structural penalty. One wave per n.
// ---------------------------------------------------------------------------
__global__ __launch_bounds__(64) void k_pen(
    const int* __restrict__ pred, const int* __restrict__ targets,
    const int* __restrict__ ilen, const int* __restrict__ tlen,
    float* __restrict__ pen) {
  __shared__ int ts[SS];
  const int n = blockIdx.x;
  const int l = threadIdx.x;

  const int tv = targets[n * SS + l];
  const bool tf = (l < tlen[n]) && (tv >= 1) && (tv <= 8);
  const unsigned long long tm = __ballot(tf);
  const int tcnt = __popcll(tm);
  if (tf) ts[__popcll(tm & ((1ull << l) - 1ull))] = tv;
  __syncthreads();

  const int L_in = ilen[n];
  int mism = 0;
  int prevc = -1;
  int base = 0;
#pragma unroll 4
  for (int c = 0; c < TT / 64; ++c) {
    const int t = c * 64 + l;
    int p = pred[n * TT + t];
    if (t >= L_in) p = 0;
    int pp = __shfl_up(p, 1);
    if (l == 0) pp = prevc;
    const bool keep = (p != pp) && (p >= 1) && (p <= 8);
    const unsigned long long m = __ballot(keep);
    const int pos = base + __popcll(m & ((1ull << l) - 1ull));
    if (keep && (pos >= tcnt || ts[pos] != p)) mism = 1;
    base += __popcll(m);
    prevc = __shfl(p, 63);
  }
  if (base != tcnt) mism = 1;
  if (__any(mism)) mism = 1;
  if (l == 0) pen[n] = mism ? 1.0f : 0.0f;
}

// ---------------------------------------------------------------------------
// Kernel 4: final mean reduction -> scalar
// ---------------------------------------------------------------------------
__global__ __launch_bounds__(64) void k_red(
    const float* __restrict__ content, const float* __restrict__ pen,
    float* __restrict__ out) {
  const int l = threadIdx.x;
  float v = content[l] + pen[l];  // STRUCT_WEIGHT = 1.0
#pragma unroll
  for (int off = 32; off; off >>= 1) v += __shfl_down(v, off);
  if (l == 0) out[0] = v * (1.0f / NN);
}

extern "C" void kernel_launch(void* const* d_in, const int* in_sizes, int n_in,
                              void* d_out, int out_size, void* d_ws,
                              size_t ws_size, hipStream_t stream) {
  const float* log_probs = (const float*)d_in[0];  // (T,N,C) f32
  const int* targets = (const int*)d_in[1];        // (N,S) i32
  const int* input_lengths = (const int*)d_in[2];  // (N,) i32
  const int* target_lengths = (const int*)d_in[3]; // (N,) i32
  float* out = (float*)d_out;

  // workspace layout (same sizes as before)
  float* Gt = (float*)d_ws;                       // [N*64][T] f32 (16 MB), log2-scaled
  float* Gb = Gt + (size_t)TT * NN * 64;          // [N][T] f32 (256 KB), log2-scaled
  int* pred = (int*)(Gb + (size_t)TT * NN);       // [N][T] i32 (256 KB)
  float* content = (float*)(pred + (size_t)NN * TT);
  float* pen = content + NN;

  k_rowpass<<<NN * (TT / 16), 256, 0, stream>>>(log_probs, targets, Gt, Gb, pred);
  k_ctc<<<NN, 64, 0, stream>>>(Gt, Gb, targets, input_lengths, target_lengths,
                               content);
  k_pen<<<NN, 64, 0, stream>>>(pred, targets, input_lengths, target_lengths,
                               pen);
  k_red<<<1, 64, 0, stream>>>(content, pen, out);
}

// Round 4
// 88.493 us; speedup vs baseline: 3.5517x; 1.2931x over previous
//
#include <hip/hip_runtime.h>
#include <hip/hip_bf16.h>
#include <cstdint>
#include <cstddef>

#define TT 1024
#define NN 64
#define CC 512
#define SS 64
#define NEGF (-1e30f)
#define LOG2E 1.4426950408889634f
#define LN2F 0.6931471805599453f

__device__ __forceinline__ float exp2i(float x) { return __builtin_amdgcn_exp2f(x); }
__device__ __forceinline__ float log2i(float x) { return __builtin_amdgcn_logf(x); }

// log-sum-exp in log2 domain
__device__ __forceinline__ float lse2(float x, float y) {
  float m = fmaxf(x, y);
  float d = fabsf(x - y);
  return m + log2i(1.0f + exp2i(-d));
}
__device__ __forceinline__ float lse3(float x, float y, float z) {
  float m = fmaxf(fmaxf(x, y), z);  // v_max3_f32
  float s = exp2i(x - m) + exp2i(y - m) + exp2i(z - m);
  return m + log2i(s);
}

// lane l gets lane l-1's value; lane 0 gets `oldv` (DPP wave_shr:1, bound_ctrl=0)
// HW-verified in round 2 (absmax 0.0).
__device__ __forceinline__ float dpp_shr1(float x, float oldv) {
  int r = __builtin_amdgcn_update_dpp(__float_as_int(oldv), __float_as_int(x),
                                      0x138 /*wave_shr:1*/, 0xF, 0xF, false);
  return __int_as_float(r);
}

// ---------------------------------------------------------------------------
// Kernel 1: fused row pass (identical to the verified round-2 version).
// Block = one n x 16 consecutive t, 4 waves. Per row: argmax -> pred, and
// log2-scaled gathers written TRANSPOSED: Gt[(n*64+s)][t], Gb[n][t].
// ---------------------------------------------------------------------------
__global__ __launch_bounds__(256) void k_rowpass(
    const float* __restrict__ lp, const int* __restrict__ targets,
    float* __restrict__ Gt, float* __restrict__ Gb, int* __restrict__ pred) {
  __shared__ float rows[4][CC];
  __shared__ float Gs[16][65];  // [t_local][s], padded
  __shared__ float Gsb[16];     // blank per t_local
  const int tid = threadIdx.x;
  const int wid = tid >> 6;
  const int l = tid & 63;
  const int n = blockIdx.x & 63;
  const int tc = blockIdx.x >> 6;  // t-chunk of 16

  const int tgt = targets[n * SS + l];

  for (int i = 0; i < 4; ++i) {
    const int tl = wid * 4 + i;  // local t in [0,16)
    const int t = tc * 16 + tl;
    const float* row = lp + ((size_t)t * NN + n) * CC;
    const float4 v0 = ((const float4*)row)[l];
    const float4 v1 = ((const float4*)row)[l + 64];
    ((float4*)rows[wid])[l] = v0;
    ((float4*)rows[wid])[l + 64] = v1;

    // argmax with first-index tiebreak
    float bv = v0.x;
    int bi = 4 * l;
#define UPD(v, idx)                                \
    do {                                           \
      if ((v) > bv || ((v) == bv && (idx) < bi)) { \
        bv = (v);                                  \
        bi = (idx);                                \
      }                                            \
    } while (0)
    UPD(v0.y, 4 * l + 1);
    UPD(v0.z, 4 * l + 2);
    UPD(v0.w, 4 * l + 3);
    UPD(v1.x, 256 + 4 * l);
    UPD(v1.y, 256 + 4 * l + 1);
    UPD(v1.z, 256 + 4 * l + 2);
    UPD(v1.w, 256 + 4 * l + 3);
#pragma unroll
    for (int off = 32; off; off >>= 1) {
      float ov = __shfl_xor(bv, off);
      int oi = __shfl_xor(bi, off);
      UPD(ov, oi);
    }
#undef UPD

    const float gv = rows[wid][tgt];
    Gs[tl][l] = gv * LOG2E;
    if (l == 0) {
      Gsb[tl] = v0.x * LOG2E;  // class 0 = lane0's v0.x
      pred[n * TT + t] = bi;
    }
  }
  __syncthreads();

  // transpose write: thread (l, q) writes t = tc*16 + q*4 .. +3 for strip l
  const int q = tid >> 6;
  float4 w;
  w.x = Gs[q * 4 + 0][l];
  w.y = Gs[q * 4 + 1][l];
  w.z = Gs[q * 4 + 2][l];
  w.w = Gs[q * 4 + 3][l];
  ((float4*)(Gt + (size_t)(n * 64 + l) * TT + tc * 16))[q] = w;
  if (tid < 16) Gb[(size_t)n * TT + tc * 16 + tid] = Gsb[tid];
}

// ---------------------------------------------------------------------------
// Kernel 2: CTC via forward/backward split, log2 domain. One block (2 waves)
// per n. Wave 0: alpha over t=0..511 (lane l: odd u=2l+1, even u=2l+2; u=0 =
// uniform blank chain a0). Wave 1: beta over t=1023..512 with REVERSED lane
// mapping (lane l holds m=63-l: odd u=2m+1, even u=2m; u=128 = uniform blank
// chain aT) so the same wave_shr:1 DPP primitive applies. Combine:
// loss = -lse_u(alpha_511[u] + B[u]).
// ---------------------------------------------------------------------------
__global__ __launch_bounds__(128) void k_ctc(
    const float* __restrict__ Gt, const float* __restrict__ Gb,
    const int* __restrict__ targets, const int* __restrict__ ilen,
    const int* __restrict__ tlen, float* __restrict__ content) {
  __shared__ float Bo[64], Be[64], BTs;
  const int n = blockIdx.x;
  const int tid = threadIdx.x;
  const int wid = tid >> 6;
  const int l = tid & 63;

  const int Lm1 = __builtin_amdgcn_readfirstlane(ilen[n]) - 1;
  const int Ltg = __builtin_amdgcn_readfirstlane(tlen[n]);

  float sp0 = NEGF, sp1 = NEGF;          // fwd snapshot (only if Lm1 < 512)
  float fe0 = NEGF, fe1 = NEGF, fa0 = NEGF;

  if (wid == 0) {
    // ---------------- forward wave: t = 0 .. 511 ----------------
    const int tgt = targets[n * SS + l];
    const int tprev = __shfl_up(tgt, 1);
    const bool skip = (l == 0) || (tgt != tprev);
    const float4* bt = (const float4*)(Gt + (size_t)(n * 64 + l) * TT);
    const float4* bb = (const float4*)(Gb + (size_t)n * TT);
    float4 ring[8], ringb[8];
#pragma unroll
    for (int i = 0; i < 8; ++i) {
      ring[i] = bt[i];
      ringb[i] = bb[i];
    }
    // virtual pre-state: applying step t=0 yields exact alpha_0
    float e0 = NEGF, e1 = NEGF, a0 = 0.0f;

#define FSTEP(GT, GB)                             \
    {                                             \
      const float upE = dpp_shr1(e0, a0);         \
      const float upO = dpp_shr1(e1, NEGF);       \
      const float z = skip ? upO : NEGF;          \
      const float n1 = lse3(e1, upE, z) + (GT);   \
      const float n0 = lse2(e0, e1) + (GB);       \
      a0 += (GB);                                 \
      e0 = n0;                                    \
      e1 = n1;                                    \
    }

    for (int g = 0; g < 16; ++g) {
#pragma unroll
      for (int ci = 0; ci < 8; ++ci) {
        const int c = g * 8 + ci;
        const float4 gt4 = ring[ci];
        const float4 gb4 = ringb[ci];
        if (c + 8 < 128) {
          ring[ci] = bt[c + 8];
          ringb[ci] = bb[c + 8];
        }
        if (__builtin_expect((unsigned)(Lm1 - c * 4) < 4u, 0)) {
          FSTEP(gt4.x, gb4.x);
          if (c * 4 + 0 == Lm1) { sp0 = e0; sp1 = e1; }
          FSTEP(gt4.y, gb4.y);
          if (c * 4 + 1 == Lm1) { sp0 = e0; sp1 = e1; }
          FSTEP(gt4.z, gb4.z);
          if (c * 4 + 2 == Lm1) { sp0 = e0; sp1 = e1; }
          FSTEP(gt4.w, gb4.w);
          if (c * 4 + 3 == Lm1) { sp0 = e0; sp1 = e1; }
        } else {
          FSTEP(gt4.x, gb4.x);
          FSTEP(gt4.y, gb4.y);
          FSTEP(gt4.z, gb4.z);
          FSTEP(gt4.w, gb4.w);
        }
      }
    }
#undef FSTEP
    fe0 = e0;
    fe1 = e1;
    fa0 = a0;
  } else {
    // ---------------- backward wave: t = 1023 .. 512 ----------------
    const int m = 63 - l;  // state index this lane owns
    const int tm = targets[n * SS + m];
    const int tmp = __shfl_up(tm, 1);  // lane l-1 holds m+1
    const bool skipb = (l > 0) && (tm != tmp);  // allow_skip into u=2m+3
    const float4* bt = (const float4*)(Gt + (size_t)(n * 64 + m) * TT);
    const float4* bb = (const float4*)(Gb + (size_t)n * TT);
    float4 ring[8], ringb[8];
#pragma unroll
    for (int i = 0; i < 8; ++i) {
      ring[i] = bt[255 - i];
      ringb[i] = bb[255 - i];
    }
    float d0 = NEGF, d1 = NEGF, aT = NEGF;

#define BSTEP(GT, GB)                             \
    {                                             \
      const float nd0 = dpp_shr1(d0, aT);         \
      const float nd1 = dpp_shr1(d1, NEGF);       \
      const float z = skipb ? nd1 : NEGF;         \
      const float n1 = lse3(d1, nd0, z) + (GT);   \
      const float n0 = lse2(d0, d1) + (GB);       \
      aT += (GB);                                 \
      d0 = n0;                                    \
      d1 = n1;                                    \
    }
#define BINIT(GT, GB)                             \
    {                                             \
      d0 = (m == Ltg) ? (GB) : NEGF;              \
      d1 = (m == Ltg - 1) ? (GT) : NEGF;          \
      aT = (Ltg == 64) ? (GB) : NEGF;             \
    }

    for (int g = 0; g < 16; ++g) {
#pragma unroll
      for (int ci = 0; ci < 8; ++ci) {
        const int cs = g * 8 + ci;
        const float4 gt4 = ring[ci];
        const float4 gb4 = ringb[ci];
        if (cs + 8 < 128) {
          ring[ci] = bt[255 - cs - 8];
          ringb[ci] = bb[255 - cs - 8];
        }
        const int thi = 1023 - 4 * cs;  // chunk covers t in [thi-3, thi]
        // component order: j=0 -> t=thi (.w), j=3 -> t=thi-3 (.x)
        if (__builtin_expect((unsigned)(thi - Lm1) < 4u, 0)) {
          if (thi - 0 == Lm1) BINIT(gt4.w, gb4.w) else BSTEP(gt4.w, gb4.w);
          if (thi - 1 == Lm1) BINIT(gt4.z, gb4.z) else BSTEP(gt4.z, gb4.z);
          if (thi - 2 == Lm1) BINIT(gt4.y, gb4.y) else BSTEP(gt4.y, gb4.y);
          if (thi - 3 == Lm1) BINIT(gt4.x, gb4.x) else BSTEP(gt4.x, gb4.x);
        } else {
          // pre-init chunks (t > Lm1) run harmless on NEG states; the
          // init chunk resets everything at t == Lm1.
          BSTEP(gt4.w, gb4.w);
          BSTEP(gt4.z, gb4.z);
          BSTEP(gt4.y, gb4.y);
          BSTEP(gt4.x, gb4.x);
        }
      }
    }
#undef BSTEP
#undef BINIT

    // boundary step (no lp add): B[u] for u = 2m+1, 2m; B[128] = aT
    const float nd0 = dpp_shr1(d0, aT);
    const float nd1 = dpp_shr1(d1, NEGF);
    Bo[m] = lse3(d1, nd0, skipb ? nd1 : NEGF);
    Be[m] = lse2(d0, d1);
    if (l == 0) BTs = aT;
  }
  __syncthreads();

  if (wid == 0) {
    float loss;
    if (Lm1 >= 512) {
      // loss = -lse_u(alpha_511[u] + B[u])
      const float to_ = fe1 + Bo[l];                          // u = 2l+1
      const float te_ = fe0 + ((l < 63) ? Be[l + 1] : BTs);   // u = 2l+2
      const float t0_ = (l == 0) ? (fa0 + Be[0]) : NEGF;      // u = 0
      float mx = fmaxf(fmaxf(to_, te_), t0_);
#pragma unroll
      for (int off = 32; off; off >>= 1) mx = fmaxf(mx, __shfl_xor(mx, off));
      float s = exp2i(to_ - mx) + exp2i(te_ - mx) +
                ((l == 0) ? exp2i(t0_ - mx) : 0.0f);
#pragma unroll
      for (int off = 32; off; off >>= 1) s += __shfl_xor(s, off);
      loss = -(mx + log2i(s)) * LN2F;
    } else {
      const float pA = __shfl(sp0, Ltg - 1);  // alpha[2*Ltg]
      const float pB = __shfl(sp1, Ltg - 1);  // alpha[2*Ltg-1]
      loss = -lse2(pA, pB) * LN2F;
    }
    if (loss > 1e20f) loss = 0.0f;
    if (!(loss <= 1e20f)) loss = 0.0f;  // NaN/inf guard
    if (l == 0) content[n] = loss;
  }
}

// ---------------------------------------------------------------------------
// Kernel 3: structural penalty. One wave per n.
// ---------------------------------------------------------------------------
__global__ __launch_bounds__(64) void k_pen(
    const int* __restrict__ pred, const int* __restrict__ targets,
    const int* __restrict__ ilen, const int* __restrict__ tlen,
    float* __restrict__ pen) {
  __shared__ int ts[SS];
  const int n = blockIdx.x;
  const int l = threadIdx.x;

  const int tv = targets[n * SS + l];
  const bool tf = (l < tlen[n]) && (tv >= 1) && (tv <= 8);
  const unsigned long long tm = __ballot(tf);
  const int tcnt = __popcll(tm);
  if (tf) ts[__popcll(tm & ((1ull << l) - 1ull))] = tv;
  __syncthreads();

  const int L_in = ilen[n];
  int mism = 0;
  int prevc = -1;
  int base = 0;
#pragma unroll 4
  for (int c = 0; c < TT / 64; ++c) {
    const int t = c * 64 + l;
    int p = pred[n * TT + t];
    if (t >= L_in) p = 0;
    int pp = __shfl_up(p, 1);
    if (l == 0) pp = prevc;
    const bool keep = (p != pp) && (p >= 1) && (p <= 8);
    const unsigned long long m = __ballot(keep);
    const int pos = base + __popcll(m & ((1ull << l) - 1ull));
    if (keep && (pos >= tcnt || ts[pos] != p)) mism = 1;
    base += __popcll(m);
    prevc = __shfl(p, 63);
  }
  if (base != tcnt) mism = 1;
  if (__any(mism)) mism = 1;
  if (l == 0) pen[n] = mism ? 1.0f : 0.0f;
}

// ---------------------------------------------------------------------------
// Kernel 4: final mean reduction -> scalar
// ---------------------------------------------------------------------------
__global__ __launch_bounds__(64) void k_red(
    const float* __restrict__ content, const float* __restrict__ pen,
    float* __restrict__ out) {
  const int l = threadIdx.x;
  float v = content[l] + pen[l];  // STRUCT_WEIGHT = 1.0
#pragma unroll
  for (int off = 32; off; off >>= 1) v += __shfl_down(v, off);
  if (l == 0) out[0] = v * (1.0f / NN);
}

extern "C" void kernel_launch(void* const* d_in, const int* in_sizes, int n_in,
                              void* d_out, int out_size, void* d_ws,
                              size_t ws_size, hipStream_t stream) {
  const float* log_probs = (const float*)d_in[0];  // (T,N,C) f32
  const int* targets = (const int*)d_in[1];        // (N,S) i32
  const int* input_lengths = (const int*)d_in[2];  // (N,) i32
  const int* target_lengths = (const int*)d_in[3]; // (N,) i32
  float* out = (float*)d_out;

  // workspace layout
  float* Gt = (float*)d_ws;                       // [N*64][T] f32 (16 MB), log2-scaled
  float* Gb = Gt + (size_t)TT * NN * 64;          // [N][T] f32 (256 KB), log2-scaled
  int* pred = (int*)(Gb + (size_t)TT * NN);       // [N][T] i32 (256 KB)
  float* content = (float*)(pred + (size_t)NN * TT);
  float* pen = content + NN;

  k_rowpass<<<NN * (TT / 16), 256, 0, stream>>>(log_probs, targets, Gt, Gb, pred);
  k_ctc<<<NN, 128, 0, stream>>>(Gt, Gb, targets, input_lengths, target_lengths,
                                content);
  k_pen<<<NN, 64, 0, stream>>>(pred, targets, input_lengths, target_lengths,
                               pen);
  k_red<<<1, 64, 0, stream>>>(content, pen, out);
}

// Round 5
// 60.845 us; speedup vs baseline: 5.1655x; 1.4544x over previous
//
#include <hip/hip_runtime.h>
#include <hip/hip_bf16.h>
#include <cstdint>
#include <cstddef>

#define TT 1024
#define NN 64
#define CC 512
#define SS 64
#define NEGF (-1e30f)
#define LN2F 0.6931471805599453f
#define SMALLE (-0x40000000)

__device__ __forceinline__ float exp2i(float x) { return __builtin_amdgcn_exp2f(x); }
__device__ __forceinline__ float log2i(float x) { return __builtin_amdgcn_logf(x); }

__device__ __forceinline__ float ldx(float x, int e) {
#if __has_builtin(__builtin_amdgcn_ldexpf)
  return __builtin_amdgcn_ldexpf(x, e);
#else
  return ldexpf(x, e);
#endif
}

// log-sum-exp in log2 domain (combine only; NEGF sentinel keeps it NaN-free)
__device__ __forceinline__ float lse2(float x, float y) {
  float m = fmaxf(x, y);
  float d = fabsf(x - y);
  return m + log2i(1.0f + exp2i(-d));
}
__device__ __forceinline__ float lse3(float x, float y, float z) {
  float m = fmaxf(fmaxf(x, y), z);
  float s = exp2i(x - m) + exp2i(y - m) + exp2i(z - m);
  return m + log2i(s);
}

// lane l gets lane l-1's value; lane 0 gets `oldv` (DPP wave_shr:1) — HW-verified R2.
__device__ __forceinline__ float dpp_shr1(float x, float oldv) {
  int r = __builtin_amdgcn_update_dpp(__float_as_int(oldv), __float_as_int(x),
                                      0x138, 0xF, 0xF, false);
  return __int_as_float(r);
}
__device__ __forceinline__ int dpp_shr1_i(int x, int oldv) {
  return __builtin_amdgcn_update_dpp(oldv, x, 0x138, 0xF, 0xF, false);
}

// Q > 0 ? log2(Q)+E : NEGF  (conversion to log domain for the combine)
__device__ __forceinline__ float q2log(float Q, int E) {
  return (Q > 0.0f) ? (log2i(Q) + (float)E) : NEGF;
}

// ---------------------------------------------------------------------------
// Kernel 1: fused row pass. Block = one n x 16 t, 4 waves. Per row: argmax ->
// pred; LINEAR weights written transposed: Wt[(n*64+s)][t] = p_t(tgt_s),
// Wb[n][t] = p_t(blank).
// ---------------------------------------------------------------------------
__global__ __launch_bounds__(256) void k_rowpass(
    const float* __restrict__ lp, const int* __restrict__ targets,
    float* __restrict__ Wt, float* __restrict__ Wb, int* __restrict__ pred) {
  __shared__ float rows[4][CC];
  __shared__ float Gs[16][65];
  __shared__ float Gsb[16];
  const int tid = threadIdx.x;
  const int wid = tid >> 6;
  const int l = tid & 63;
  const int n = blockIdx.x & 63;
  const int tc = blockIdx.x >> 6;

  const int tgt = targets[n * SS + l];

  for (int i = 0; i < 4; ++i) {
    const int tl = wid * 4 + i;
    const int t = tc * 16 + tl;
    const float* row = lp + ((size_t)t * NN + n) * CC;
    const float4 v0 = ((const float4*)row)[l];
    const float4 v1 = ((const float4*)row)[l + 64];
    ((float4*)rows[wid])[l] = v0;
    ((float4*)rows[wid])[l + 64] = v1;

    float bv = v0.x;
    int bi = 4 * l;
#define UPD(v, idx)                                \
    do {                                           \
      if ((v) > bv || ((v) == bv && (idx) < bi)) { \
        bv = (v);                                  \
        bi = (idx);                                \
      }                                            \
    } while (0)
    UPD(v0.y, 4 * l + 1);
    UPD(v0.z, 4 * l + 2);
    UPD(v0.w, 4 * l + 3);
    UPD(v1.x, 256 + 4 * l);
    UPD(v1.y, 256 + 4 * l + 1);
    UPD(v1.z, 256 + 4 * l + 2);
    UPD(v1.w, 256 + 4 * l + 3);
#pragma unroll
    for (int off = 32; off; off >>= 1) {
      float ov = __shfl_xor(bv, off);
      int oi = __shfl_xor(bi, off);
      UPD(ov, oi);
    }
#undef UPD

    const float gv = rows[wid][tgt];
    Gs[tl][l] = __expf(gv);  // linear p
    if (l == 0) {
      Gsb[tl] = __expf(v0.x);  // linear blank p
      pred[n * TT + t] = bi;
    }
  }
  __syncthreads();

  const int q = tid >> 6;
  float4 w;
  w.x = Gs[q * 4 + 0][l];
  w.y = Gs[q * 4 + 1][l];
  w.z = Gs[q * 4 + 2][l];
  w.w = Gs[q * 4 + 3][l];
  ((float4*)(Wt + (size_t)(n * 64 + l) * TT + tc * 16))[q] = w;
  if (tid < 16) Wb[(size_t)n * TT + tc * 16 + tid] = Gsb[tid];
}

// ---------------------------------------------------------------------------
// Kernel 2: CTC fwd/bwd in LINEAR domain with per-lane exponent frames,
// + fused structural penalty. One block (3 waves) per n:
//   wave 0: alpha t=0..511   (lane l: odd u=2l+1 -> Q1, even u=2l+2 -> Q0,
//                             u=0 -> uniform chain Qa*2^Ea)
//   wave 1: beta  t=1023..512 (reversed lanes, m=63-l; u=128 chain QaT)
//   wave 2: structural penalty
// True alpha (log2) = log2(Q) + E. Renorm every 4 steps: exponent extract via
// bit ops + int DPP neighbor sync; NO transcendentals in the recurrence.
// ---------------------------------------------------------------------------
__global__ __launch_bounds__(192) void k_ctc(
    const float* __restrict__ Wt, const float* __restrict__ Wb,
    const int* __restrict__ targets, const int* __restrict__ ilen,
    const int* __restrict__ tlen, const int* __restrict__ pred,
    float* __restrict__ content, float* __restrict__ pen) {
  __shared__ float Bo[64], Be[64], BTs;
  __shared__ int ts[SS];
  const int n = blockIdx.x;
  const int tid = threadIdx.x;
  const int wid = tid >> 6;
  const int l = tid & 63;

  const int Lm1 = __builtin_amdgcn_readfirstlane(ilen[n]) - 1;
  const int Ltg = __builtin_amdgcn_readfirstlane(tlen[n]);

  float fe0 = NEGF, fe1 = NEGF, fa0 = NEGF;
  float s0L = NEGF, s1L = NEGF;  // snapshot (Lm1 < 512), log2

  if (wid == 0) {
    // ---------------- forward wave: t = 0 .. 511 ----------------
    const int tgt = targets[n * SS + l];
    const int tprev = __shfl_up(tgt, 1);
    const float skipf = ((l == 0) || (tgt != tprev)) ? 1.0f : 0.0f;
    const float4* bt = (const float4*)(Wt + (size_t)(n * 64 + l) * TT);
    const float4* bb = (const float4*)(Wb + (size_t)n * TT);
    float4 ring[8], ringb[8];
#pragma unroll
    for (int i = 0; i < 8; ++i) {
      ring[i] = bt[i];
      ringb[i] = bb[i];
    }

    float Q0 = 0.0f, Q1 = 0.0f, Qa = 1.0f;
    int E = 0, Ea = 0, dEnb = 0, dEa = 0;
    float sQ0 = 0.0f, sQ1 = 0.0f;
    int sE = 0;

#define FSTEP(WTv, WBv)                              \
    {                                                \
      const float a0f = ldx(Qa, dEa);                \
      const float up0 = dpp_shr1(Q0, a0f);           \
      const float up1 = dpp_shr1(Q1, 0.0f);          \
      const float uu = fmaf(skipf, up1, up0);        \
      const float us = ldx(uu, dEnb);                \
      const float n1 = (Q1 + us) * (WTv);            \
      const float n0 = (Q0 + Q1) * (WBv);            \
      Qa *= (WBv);                                   \
      Q0 = n0;                                       \
      Q1 = n1;                                       \
    }
#define FRENORM                                               \
    {                                                         \
      const float mq = fmaxf(Q0, Q1);                         \
      const int eo = (mq > 0.0f)                              \
          ? (E + (((__float_as_int(mq) >> 23) & 255) - 127))  \
          : SMALLE;                                           \
      const int en = dpp_shr1_i(eo, SMALLE);                  \
      int En = (eo > en) ? eo : en;                           \
      if (En == SMALLE) En = E;                               \
      const int sh = E - En;                                  \
      Q0 = ldx(Q0, sh);                                       \
      Q1 = ldx(Q1, sh);                                       \
      E = En;                                                 \
      const int Eup = dpp_shr1_i(E, E);                       \
      dEnb = Eup - E;                                         \
      const int exa = ((__float_as_int(Qa) >> 23) & 255) - 127; \
      Ea += exa;                                              \
      Qa = ldx(Qa, -exa);                                     \
      dEa = Ea - E;                                           \
    }

    for (int g = 0; g < 16; ++g) {
#pragma unroll
      for (int ci = 0; ci < 8; ++ci) {
        const int c = g * 8 + ci;
        const float4 wt4 = ring[ci];
        const float4 wb4 = ringb[ci];
        ring[ci] = bt[c + 8];   // overshoot reads stay inside d_ws
        ringb[ci] = bb[c + 8];
        if (__builtin_expect((unsigned)(Lm1 - c * 4) < 4u, 0)) {
          FSTEP(wt4.x, wb4.x);
          if (c * 4 + 0 == Lm1) { sQ0 = Q0; sQ1 = Q1; sE = E; }
          FSTEP(wt4.y, wb4.y);
          if (c * 4 + 1 == Lm1) { sQ0 = Q0; sQ1 = Q1; sE = E; }
          FSTEP(wt4.z, wb4.z);
          if (c * 4 + 2 == Lm1) { sQ0 = Q0; sQ1 = Q1; sE = E; }
          FSTEP(wt4.w, wb4.w);
          if (c * 4 + 3 == Lm1) { sQ0 = Q0; sQ1 = Q1; sE = E; }
        } else {
          FSTEP(wt4.x, wb4.x);
          FSTEP(wt4.y, wb4.y);
          FSTEP(wt4.z, wb4.z);
          FSTEP(wt4.w, wb4.w);
        }
        FRENORM;
      }
    }
#undef FSTEP
#undef FRENORM
    fe0 = q2log(Q0, E);
    fe1 = q2log(Q1, E);
    fa0 = q2log(Qa, Ea);
    s0L = q2log(sQ0, sE);
    s1L = q2log(sQ1, sE);
  } else if (wid == 1) {
    // ---------------- backward wave: t = 1023 .. 512 ----------------
    const int m = 63 - l;
    const int tm = targets[n * SS + m];
    const int tmp = __shfl_up(tm, 1);  // lane l-1 holds m+1
    const float skipbf = ((l > 0) && (tm != tmp)) ? 1.0f : 0.0f;
    const float4* bt = (const float4*)(Wt + (size_t)(n * 64 + m) * TT);
    const float4* bb = (const float4*)(Wb + (size_t)n * TT);
    float4 ring[8], ringb[8];
#pragma unroll
    for (int i = 0; i < 8; ++i) {
      ring[i] = bt[255 - i];
      ringb[i] = bb[255 - i];
    }

    float Qd0 = 0.0f, Qd1 = 0.0f, QaT = 0.0f;
    int Eb = 0, EaT = 0, dEnb = 0, dEa = 0;

#define BSTEP(WTv, WBv)                              \
    {                                                \
      const float aTf = ldx(QaT, dEa);               \
      const float nd0 = dpp_shr1(Qd0, aTf);          \
      const float nd1 = dpp_shr1(Qd1, 0.0f);         \
      const float uu = fmaf(skipbf, nd1, nd0);       \
      const float us = ldx(uu, dEnb);                \
      const float n1 = (Qd1 + us) * (WTv);           \
      const float n0 = (Qd0 + Qd1) * (WBv);          \
      QaT *= (WBv);                                  \
      Qd0 = n0;                                      \
      Qd1 = n1;                                      \
    }
#define BINIT(WTv, WBv)                              \
    {                                                \
      Qd0 = (m == Ltg) ? (WBv) : 0.0f;               \
      Qd1 = (m == Ltg - 1) ? (WTv) : 0.0f;           \
      QaT = (Ltg == 64) ? (WBv) : 0.0f;              \
      Eb = 0; EaT = 0; dEnb = 0; dEa = 0;            \
    }
#define BRENORM                                               \
    {                                                         \
      const float mq = fmaxf(Qd0, Qd1);                       \
      const int eo = (mq > 0.0f)                              \
          ? (Eb + (((__float_as_int(mq) >> 23) & 255) - 127)) \
          : SMALLE;                                           \
      const int en = dpp_shr1_i(eo, SMALLE);                  \
      int En = (eo > en) ? eo : en;                           \
      if (En == SMALLE) En = Eb;                              \
      const int sh = Eb - En;                                 \
      Qd0 = ldx(Qd0, sh);                                     \
      Qd1 = ldx(Qd1, sh);                                     \
      Eb = En;                                                \
      const int Eup = dpp_shr1_i(Eb, Eb);                     \
      dEnb = Eup - Eb;                                        \
      if (QaT > 0.0f) {                                       \
        const int exa = ((__float_as_int(QaT) >> 23) & 255) - 127; \
        EaT += exa;                                           \
        QaT = ldx(QaT, -exa);                                 \
      }                                                       \
      dEa = EaT - Eb;                                         \
    }

    for (int g = 0; g < 16; ++g) {
#pragma unroll
      for (int ci = 0; ci < 8; ++ci) {
        const int cs = g * 8 + ci;
        const float4 wt4 = ring[ci];
        const float4 wb4 = ringb[ci];
        ring[ci] = bt[255 - cs - 8];
        ringb[ci] = bb[255 - cs - 8];
        const int thi = 1023 - 4 * cs;
        if (__builtin_expect((unsigned)(thi - Lm1) < 4u, 0)) {
          if (thi - 0 == Lm1) BINIT(wt4.w, wb4.w) else BSTEP(wt4.w, wb4.w);
          if (thi - 1 == Lm1) BINIT(wt4.z, wb4.z) else BSTEP(wt4.z, wb4.z);
          if (thi - 2 == Lm1) BINIT(wt4.y, wb4.y) else BSTEP(wt4.y, wb4.y);
          if (thi - 3 == Lm1) BINIT(wt4.x, wb4.x) else BSTEP(wt4.x, wb4.x);
        } else {
          BSTEP(wt4.w, wb4.w);
          BSTEP(wt4.z, wb4.z);
          BSTEP(wt4.y, wb4.y);
          BSTEP(wt4.x, wb4.x);
        }
        BRENORM;
      }
    }
#undef BSTEP
#undef BINIT
#undef BRENORM

    // convert to log2 and do the boundary combine step (round-4-verified)
    const float d0L = q2log(Qd0, Eb);
    const float d1L = q2log(Qd1, Eb);
    const float aTL = q2log(QaT, EaT);
    const float nd0 = dpp_shr1(d0L, aTL);
    const float nd1 = dpp_shr1(d1L, NEGF);
    const float skz = ((l > 0) && (tm != tmp)) ? nd1 : NEGF;
    Bo[m] = lse3(d1L, nd0, skz);
    Be[m] = lse2(d0L, d1L);
    if (l == 0) BTs = aTL;
  } else {
    // ---------------- penalty wave ----------------
    const int tv = targets[n * SS + l];
    const bool tf = (l < Ltg) && (tv >= 1) && (tv <= 8);
    const unsigned long long tmk = __ballot(tf);
    const int tcnt = __popcll(tmk);
    if (tf) ts[__popcll(tmk & ((1ull << l) - 1ull))] = tv;
    // same-wave LDS write->read is in-order; no block barrier needed here

    const int L_in = Lm1 + 1;
    int mism = 0;
    int prevc = -1;
    int base = 0;
#pragma unroll 4
    for (int c = 0; c < TT / 64; ++c) {
      const int t = c * 64 + l;
      int p = pred[n * TT + t];
      if (t >= L_in) p = 0;
      int pp = __shfl_up(p, 1);
      if (l == 0) pp = prevc;
      const bool keep = (p != pp) && (p >= 1) && (p <= 8);
      const unsigned long long mk = __ballot(keep);
      const int pos = base + __popcll(mk & ((1ull << l) - 1ull));
      if (keep && (pos >= tcnt || ts[pos] != p)) mism = 1;
      base += __popcll(mk);
      prevc = __shfl(p, 63);
    }
    if (base != tcnt) mism = 1;
    if (__any(mism)) mism = 1;
    if (l == 0) pen[n] = mism ? 1.0f : 0.0f;
  }

  __syncthreads();

  if (wid == 0) {
    float loss;
    if (Lm1 >= 512) {
      const float to_ = fe1 + Bo[l];                         // u = 2l+1
      const float te_ = fe0 + ((l < 63) ? Be[l + 1] : BTs);  // u = 2l+2
      const float t0_ = (l == 0) ? (fa0 + Be[0]) : NEGF;     // u = 0
      float mx = fmaxf(fmaxf(to_, te_), t0_);
#pragma unroll
      for (int off = 32; off; off >>= 1) mx = fmaxf(mx, __shfl_xor(mx, off));
      float s = exp2i(to_ - mx) + exp2i(te_ - mx) +
                ((l == 0) ? exp2i(t0_ - mx) : 0.0f);
#pragma unroll
      for (int off = 32; off; off >>= 1) s += __shfl_xor(s, off);
      loss = -(mx + log2i(s)) * LN2F;
    } else {
      const float pA = __shfl(s0L, Ltg - 1);  // alpha[2*Ltg]
      const float pB = __shfl(s1L, Ltg - 1);  // alpha[2*Ltg-1]
      loss = -lse2(pA, pB) * LN2F;
    }
    if (loss > 1e20f) loss = 0.0f;
    if (!(loss <= 1e20f)) loss = 0.0f;  // NaN guard
    if (l == 0) content[n] = loss;
  }
}

// ---------------------------------------------------------------------------
// Kernel 3: final mean reduction -> scalar
// ---------------------------------------------------------------------------
__global__ __launch_bounds__(64) void k_red(
    const float* __restrict__ content, const float* __restrict__ pen,
    float* __restrict__ out) {
  const int l = threadIdx.x;
  float v = content[l] + pen[l];  // STRUCT_WEIGHT = 1.0
#pragma unroll
  for (int off = 32; off; off >>= 1) v += __shfl_down(v, off);
  if (l == 0) out[0] = v * (1.0f / NN);
}

extern "C" void kernel_launch(void* const* d_in, const int* in_sizes, int n_in,
                              void* d_out, int out_size, void* d_ws,
                              size_t ws_size, hipStream_t stream) {
  const float* log_probs = (const float*)d_in[0];  // (T,N,C) f32
  const int* targets = (const int*)d_in[1];        // (N,S) i32
  const int* input_lengths = (const int*)d_in[2];  // (N,) i32
  const int* target_lengths = (const int*)d_in[3]; // (N,) i32
  float* out = (float*)d_out;

  // workspace layout
  float* Wt = (float*)d_ws;                        // [N*64][T] f32 (16 MB), linear p
  float* Wb = Wt + (size_t)TT * NN * 64;           // [N][T] f32 (256 KB), linear p
  int* pred = (int*)(Wb + (size_t)TT * NN);        // [N][T] i32 (256 KB)
  float* content = (float*)(pred + (size_t)NN * TT);
  float* pen = content + NN;

  k_rowpass<<<NN * (TT / 16), 256, 0, stream>>>(log_probs, targets, Wt, Wb, pred);
  k_ctc<<<NN, 192, 0, stream>>>(Wt, Wb, targets, input_lengths, target_lengths,
                                pred, content, pen);
  k_red<<<1, 64, 0, stream>>>(content, pen, out);
}

// Round 7
// 57.122 us; speedup vs baseline: 5.5022x; 1.0652x over previous
//
#include <hip/hip_runtime.h>
#include <hip/hip_bf16.h>
#include <cstdint>
#include <cstddef>

#define TT 1024
#define NN 64
#define CC 512
#define SS 64
#define NEGF (-1e30f)
#define LN2F 0.6931471805599453f
#define SMALLE (-0x40000000)

__device__ __forceinline__ float exp2i(float x) { return __builtin_amdgcn_exp2f(x); }
__device__ __forceinline__ float log2i(float x) { return __builtin_amdgcn_logf(x); }

__device__ __forceinline__ float ldx(float x, int e) {
#if __has_builtin(__builtin_amdgcn_ldexpf)
  return __builtin_amdgcn_ldexpf(x, e);
#else
  return ldexpf(x, e);
#endif
}

// log-sum-exp in log2 domain (final combine only)
__device__ __forceinline__ float lse2(float x, float y) {
  float m = fmaxf(x, y);
  float d = fabsf(x - y);
  return m + log2i(1.0f + exp2i(-d));
}
__device__ __forceinline__ float lse3(float x, float y, float z) {
  float m = fmaxf(fmaxf(x, y), z);
  float s = exp2i(x - m) + exp2i(y - m) + exp2i(z - m);
  return m + log2i(s);
}

// lane l gets lane l-1's value; lane 0 gets `oldv` (DPP wave_shr:1) — HW-verified R2/R5.
__device__ __forceinline__ float dpp_shr1(float x, float oldv) {
  int r = __builtin_amdgcn_update_dpp(__float_as_int(oldv), __float_as_int(x),
                                      0x138, 0xF, 0xF, false);
  return __int_as_float(r);
}
__device__ __forceinline__ int dpp_shr1_i(int x, int oldv) {
  return __builtin_amdgcn_update_dpp(oldv, x, 0x138, 0xF, 0xF, false);
}

// one u64-max DPP reduction step (old = self: uncovered lanes keep own key)
template <int CTRL>
__device__ __forceinline__ unsigned long long dpp_umax64(unsigned long long k) {
  const int lo = (int)(unsigned)k;
  const int hi = (int)(unsigned)(k >> 32);
  const int slo = __builtin_amdgcn_update_dpp(lo, lo, CTRL, 0xF, 0xF, false);
  const int shi = __builtin_amdgcn_update_dpp(hi, hi, CTRL, 0xF, 0xF, false);
  const unsigned long long o =
      ((unsigned long long)(unsigned)shi << 32) | (unsigned)slo;
  return o > k ? o : k;
}

// argmax key: monotone for log-softmax values (all < 0). Low bits: 511-idx
// so max picks the FIRST index on exact ties.
__device__ __forceinline__ unsigned long long akey(float v, int idx) {
  return ((unsigned long long)(~__float_as_uint(v)) << 32) |
         (unsigned)(511 - idx);
}
__device__ __forceinline__ unsigned long long umax64(unsigned long long a,
                                                     unsigned long long b) {
  return a > b ? a : b;
}

// f32 -> bf16 RNE (inputs are finite positive probs in [1e-6, 1])
__device__ __forceinline__ unsigned bf16rne(float f) {
  unsigned u = __float_as_uint(f);
  return (u + 0x7FFFu + ((u >> 16) & 1u)) >> 16;
}

// bf16 halves of a u32 -> f32
#define BF_LO(r) __uint_as_float((r) << 16)
#define BF_HI(r) __uint_as_float((r) & 0xFFFF0000u)

// ---------------------------------------------------------------------------
// Kernel 1: fused row pass. Block = one n x 16 t, 4 waves. Per row:
//  - argmax via packed-u64 DPP reduce (pure VALU, no LDS-pipe shuffles)
//  - LINEAR target weights, bf16, transposed: Wt16[(n*64+s)][t]
//  - blank weight f32: Wb[n][t]
// ---------------------------------------------------------------------------
__global__ __launch_bounds__(256) void k_rowpass(
    const float* __restrict__ lp, const int* __restrict__ targets,
    unsigned short* __restrict__ Wt16, float* __restrict__ Wb,
    int* __restrict__ pred) {
  __shared__ float rows[4][CC];
  __shared__ float Gs[16][65];
  __shared__ float Gsb[16];
  const int tid = threadIdx.x;
  const int wid = tid >> 6;
  const int l = tid & 63;
  const int n = blockIdx.x & 63;
  const int tc = blockIdx.x >> 6;

  const int tgt = targets[n * SS + l];

  for (int i = 0; i < 4; ++i) {
    const int tl = wid * 4 + i;
    const int t = tc * 16 + tl;
    const float* row = lp + ((size_t)t * NN + n) * CC;
    const float4 v0 = ((const float4*)row)[l];
    const float4 v1 = ((const float4*)row)[l + 64];
    ((float4*)rows[wid])[l] = v0;
    ((float4*)rows[wid])[l + 64] = v1;

    // argmax: packed u64 keys, local tree + DPP wave reduce (lane 63 valid)
    const unsigned long long ka =
        umax64(akey(v0.x, 4 * l), akey(v0.y, 4 * l + 1));
    const unsigned long long kb =
        umax64(akey(v0.z, 4 * l + 2), akey(v0.w, 4 * l + 3));
    const unsigned long long kc =
        umax64(akey(v1.x, 256 + 4 * l), akey(v1.y, 256 + 4 * l + 1));
    const unsigned long long kd =
        umax64(akey(v1.z, 256 + 4 * l + 2), akey(v1.w, 256 + 4 * l + 3));
    unsigned long long k = umax64(umax64(ka, kb), umax64(kc, kd));
    k = dpp_umax64<0x111>(k);  // row_shr:1
    k = dpp_umax64<0x112>(k);  // row_shr:2
    k = dpp_umax64<0x114>(k);  // row_shr:4
    k = dpp_umax64<0x118>(k);  // row_shr:8
    k = dpp_umax64<0x142>(k);  // row_bcast:15
    k = dpp_umax64<0x143>(k);  // row_bcast:31

    const float gv = rows[wid][tgt];
    Gs[tl][l] = __expf(gv);  // linear p(tgt)
    if (l == 63) pred[n * TT + t] = 511 - (int)(unsigned)k;
    if (l == 0) Gsb[tl] = __expf(v0.x);  // linear p(blank)
  }
  __syncthreads();

  // transpose write: thread (l, q) packs 4 t's (bf16) for strip l
  const int q = tid >> 6;
  uint2 wv;
  wv.x = bf16rne(Gs[q * 4 + 0][l]) | (bf16rne(Gs[q * 4 + 1][l]) << 16);
  wv.y = bf16rne(Gs[q * 4 + 2][l]) | (bf16rne(Gs[q * 4 + 3][l]) << 16);
  *(uint2*)(Wt16 + (size_t)(n * 64 + l) * TT + tc * 16 + q * 4) = wv;
  if (tid < 16) Wb[(size_t)n * TT + tc * 16 + tid] = Gsb[tid];
}

// ---------------------------------------------------------------------------
// Kernel 2: CTC fwd/bwd in LINEAR domain with per-lane exponent frames
// (EXACT round-5-verified recursion: separate blank-chain exponents Ea/EaT),
// + fused structural penalty. One block (3 waves) per n:
//   wave 0: alpha t=0..511   (lane l: odd u=2l+1 -> Q1, even u=2l+2 -> Q0,
//                             u=0 -> uniform chain Qa*2^Ea)
//   wave 1: beta  t=1023..512 (reversed lanes, m=63-l; u=128 chain QaT)
//   wave 2: structural penalty
// True alpha (log2) = log2(Q) + E. Renorm every 4 steps: exponent extract via
// bit ops + int DPP neighbor sync; NO transcendentals in the recurrence.
// Only change vs R5: Wt is bf16 (unpacked to f32 at the FSTEP call sites).
// ---------------------------------------------------------------------------
__global__ __launch_bounds__(192) void k_ctc(
    const unsigned short* __restrict__ Wt16, const float* __restrict__ Wb,
    const int* __restrict__ targets, const int* __restrict__ ilen,
    const int* __restrict__ tlen, const int* __restrict__ pred,
    float* __restrict__ content, float* __restrict__ pen) {
  __shared__ float Bo[64], Be[64], BTs;
  __shared__ int ts[SS];
  const int n = blockIdx.x;
  const int tid = threadIdx.x;
  const int wid = tid >> 6;
  const int l = tid & 63;

  const int Lm1 = __builtin_amdgcn_readfirstlane(ilen[n]) - 1;
  const int Ltg = __builtin_amdgcn_readfirstlane(tlen[n]);

  float fe0 = NEGF, fe1 = NEGF, fa0 = NEGF;
  float s0L = NEGF, s1L = NEGF;  // snapshot (Lm1 < 512), log2

  if (wid == 0) {
    // ---------------- forward wave: t = 0 .. 511 ----------------
    const int tgt = targets[n * SS + l];
    const int tprev = __shfl_up(tgt, 1);
    const float skipf = ((l == 0) || (tgt != tprev)) ? 1.0f : 0.0f;
    const uint2* bt = (const uint2*)(Wt16 + (size_t)(n * 64 + l) * TT);
    const float4* bb = (const float4*)(Wb + (size_t)n * TT);
    uint2 ring[8];
    float4 ringb[8];
#pragma unroll
    for (int i = 0; i < 8; ++i) {
      ring[i] = bt[i];
      ringb[i] = bb[i];
    }

    float Q0 = 0.0f, Q1 = 0.0f, Qa = 1.0f;
    int E = 0, Ea = 0, dEnb = 0, dEa = 0;
    float sQ0 = 0.0f, sQ1 = 0.0f;
    int sE = 0;

#define FSTEP(WTv, WBv)                              \
    {                                                \
      const float a0f = ldx(Qa, dEa);                \
      const float up0 = dpp_shr1(Q0, a0f);           \
      const float up1 = dpp_shr1(Q1, 0.0f);          \
      const float uu = fmaf(skipf, up1, up0);        \
      const float us = ldx(uu, dEnb);                \
      const float n1 = (Q1 + us) * (WTv);            \
      const float n0 = (Q0 + Q1) * (WBv);            \
      Qa *= (WBv);                                   \
      Q0 = n0;                                       \
      Q1 = n1;                                       \
    }
#define FRENORM                                               \
    {                                                         \
      const float mq = fmaxf(Q0, Q1);                         \
      const int eo = (mq > 0.0f)                              \
          ? (E + (((__float_as_int(mq) >> 23) & 255) - 127))  \
          : SMALLE;                                           \
      const int en = dpp_shr1_i(eo, SMALLE);                  \
      int En = (eo > en) ? eo : en;                           \
      if (En == SMALLE) En = E;                               \
      const int sh = E - En;                                  \
      Q0 = ldx(Q0, sh);                                       \
      Q1 = ldx(Q1, sh);                                       \
      E = En;                                                 \
      const int Eup = dpp_shr1_i(E, E);                       \
      dEnb = Eup - E;                                         \
      const int exa = ((__float_as_int(Qa) >> 23) & 255) - 127; \
      Ea += exa;                                              \
      Qa = ldx(Qa, -exa);                                     \
      dEa = Ea - E;                                           \
    }

    for (int g = 0; g < 16; ++g) {
#pragma unroll
      for (int ci = 0; ci < 8; ++ci) {
        const int c = g * 8 + ci;
        const uint2 wt4 = ring[ci];
        const float4 wb4 = ringb[ci];
        ring[ci] = bt[c + 8];  // overshoot stays inside the strip
        ringb[ci] = bb[c + 8];
        if (__builtin_expect((unsigned)(Lm1 - c * 4) < 4u, 0)) {
          FSTEP(BF_LO(wt4.x), wb4.x);
          if (c * 4 + 0 == Lm1) { sQ0 = Q0; sQ1 = Q1; sE = E; }
          FSTEP(BF_HI(wt4.x), wb4.y);
          if (c * 4 + 1 == Lm1) { sQ0 = Q0; sQ1 = Q1; sE = E; }
          FSTEP(BF_LO(wt4.y), wb4.z);
          if (c * 4 + 2 == Lm1) { sQ0 = Q0; sQ1 = Q1; sE = E; }
          FSTEP(BF_HI(wt4.y), wb4.w);
          if (c * 4 + 3 == Lm1) { sQ0 = Q0; sQ1 = Q1; sE = E; }
        } else {
          FSTEP(BF_LO(wt4.x), wb4.x);
          FSTEP(BF_HI(wt4.x), wb4.y);
          FSTEP(BF_LO(wt4.y), wb4.z);
          FSTEP(BF_HI(wt4.y), wb4.w);
        }
        FRENORM;
      }
    }
#undef FSTEP
#undef FRENORM
    const float fE = (float)E;
    fe0 = (Q0 > 0.0f) ? (log2i(Q0) + fE) : NEGF;
    fe1 = (Q1 > 0.0f) ? (log2i(Q1) + fE) : NEGF;
    fa0 = (Qa > 0.0f) ? (log2i(Qa) + (float)Ea) : NEGF;
    s0L = (sQ0 > 0.0f) ? (log2i(sQ0) + (float)sE) : NEGF;
    s1L = (sQ1 > 0.0f) ? (log2i(sQ1) + (float)sE) : NEGF;
  } else if (wid == 1) {
    // ---------------- backward wave: t = 1023 .. 512 ----------------
    const int m = 63 - l;
    const int tm = targets[n * SS + m];
    const int tmp = __shfl_up(tm, 1);  // lane l-1 holds m+1
    const float skipbf = ((l > 0) && (tm != tmp)) ? 1.0f : 0.0f;
    const uint2* bt = (const uint2*)(Wt16 + (size_t)(n * 64 + m) * TT);
    const float4* bb = (const float4*)(Wb + (size_t)n * TT);
    uint2 ring[8];
    float4 ringb[8];
#pragma unroll
    for (int i = 0; i < 8; ++i) {
      ring[i] = bt[255 - i];
      ringb[i] = bb[255 - i];
    }

    float Qd0 = 0.0f, Qd1 = 0.0f, QaT = 0.0f;
    int Eb = 0, EaT = 0, dEnb = 0, dEa = 0;

#define BSTEP(WTv, WBv)                              \
    {                                                \
      const float aTf = ldx(QaT, dEa);               \
      const float nd0 = dpp_shr1(Qd0, aTf);          \
      const float nd1 = dpp_shr1(Qd1, 0.0f);         \
      const float uu = fmaf(skipbf, nd1, nd0);       \
      const float us = ldx(uu, dEnb);                \
      const float n1 = (Qd1 + us) * (WTv);           \
      const float n0 = (Qd0 + Qd1) * (WBv);          \
      QaT *= (WBv);                                  \
      Qd0 = n0;                                      \
      Qd1 = n1;                                      \
    }
#define BINIT(WTv, WBv)                              \
    {                                                \
      Qd0 = (m == Ltg) ? (WBv) : 0.0f;               \
      Qd1 = (m == Ltg - 1) ? (WTv) : 0.0f;           \
      QaT = (Ltg == 64) ? (WBv) : 0.0f;              \
      Eb = 0; EaT = 0; dEnb = 0; dEa = 0;            \
    }
#define BRENORM                                               \
    {                                                         \
      const float mq = fmaxf(Qd0, Qd1);                       \
      const int eo = (mq > 0.0f)                              \
          ? (Eb + (((__float_as_int(mq) >> 23) & 255) - 127)) \
          : SMALLE;                                           \
      const int en = dpp_shr1_i(eo, SMALLE);                  \
      int En = (eo > en) ? eo : en;                           \
      if (En == SMALLE) En = Eb;                              \
      const int sh = Eb - En;                                 \
      Qd0 = ldx(Qd0, sh);                                     \
      Qd1 = ldx(Qd1, sh);                                     \
      Eb = En;                                                \
      const int Eup = dpp_shr1_i(Eb, Eb);                     \
      dEnb = Eup - Eb;                                        \
      if (QaT > 0.0f) {                                       \
        const int exa = ((__float_as_int(QaT) >> 23) & 255) - 127; \
        EaT += exa;                                           \
        QaT = ldx(QaT, -exa);                                 \
      }                                                       \
      dEa = EaT - Eb;                                         \
    }

    for (int g = 0; g < 16; ++g) {
#pragma unroll
      for (int ci = 0; ci < 8; ++ci) {
        const int cs = g * 8 + ci;
        const uint2 wt4 = ring[ci];
        const float4 wb4 = ringb[ci];
        ring[ci] = bt[255 - cs - 8];
        ringb[ci] = bb[255 - cs - 8];
        const int thi = 1023 - 4 * cs;
        if (__builtin_expect((unsigned)(thi - Lm1) < 4u, 0)) {
          if (thi - 0 == Lm1) BINIT(BF_HI(wt4.y), wb4.w) else BSTEP(BF_HI(wt4.y), wb4.w);
          if (thi - 1 == Lm1) BINIT(BF_LO(wt4.y), wb4.z) else BSTEP(BF_LO(wt4.y), wb4.z);
          if (thi - 2 == Lm1) BINIT(BF_HI(wt4.x), wb4.y) else BSTEP(BF_HI(wt4.x), wb4.y);
          if (thi - 3 == Lm1) BINIT(BF_LO(wt4.x), wb4.x) else BSTEP(BF_LO(wt4.x), wb4.x);
        } else {
          BSTEP(BF_HI(wt4.y), wb4.w);
          BSTEP(BF_LO(wt4.y), wb4.z);
          BSTEP(BF_HI(wt4.x), wb4.y);
          BSTEP(BF_LO(wt4.x), wb4.x);
        }
        BRENORM;
      }
    }
#undef BSTEP
#undef BINIT
#undef BRENORM

    // convert to log2; boundary combine step (round-4-verified shape)
    const float fEb = (float)Eb;
    const float d0L = (Qd0 > 0.0f) ? (log2i(Qd0) + fEb) : NEGF;
    const float d1L = (Qd1 > 0.0f) ? (log2i(Qd1) + fEb) : NEGF;
    const float aTL = (QaT > 0.0f) ? (log2i(QaT) + (float)EaT) : NEGF;
    const float nd0 = dpp_shr1(d0L, aTL);
    const float nd1 = dpp_shr1(d1L, NEGF);
    const float skz = ((l > 0) && (tm != tmp)) ? nd1 : NEGF;
    Bo[m] = lse3(d1L, nd0, skz);
    Be[m] = lse2(d0L, d1L);
    if (l == 0) BTs = aTL;
  } else {
    // ---------------- penalty wave ----------------
    const int tv = targets[n * SS + l];
    const bool tf = (l < Ltg) && (tv >= 1) && (tv <= 8);
    const unsigned long long tmk = __ballot(tf);
    const int tcnt = __popcll(tmk);
    if (tf) ts[__popcll(tmk & ((1ull << l) - 1ull))] = tv;

    const int L_in = Lm1 + 1;
    int mism = 0;
    int prevc = -1;
    int base = 0;
#pragma unroll 4
    for (int c = 0; c < TT / 64; ++c) {
      const int t = c * 64 + l;
      int p = pred[n * TT + t];
      if (t >= L_in) p = 0;
      int pp = __shfl_up(p, 1);
      if (l == 0) pp = prevc;
      const bool keep = (p != pp) && (p >= 1) && (p <= 8);
      const unsigned long long mk = __ballot(keep);
      const int pos = base + __popcll(mk & ((1ull << l) - 1ull));
      if (keep && (pos >= tcnt || ts[pos] != p)) mism = 1;
      base += __popcll(mk);
      prevc = __shfl(p, 63);
    }
    if (base != tcnt) mism = 1;
    if (__any(mism)) mism = 1;
    if (l == 0) pen[n] = mism ? 1.0f : 0.0f;
  }

  __syncthreads();

  if (wid == 0) {
    float loss;
    if (Lm1 >= 512) {
      const float to_ = fe1 + Bo[l];                         // u = 2l+1
      const float te_ = fe0 + ((l < 63) ? Be[l + 1] : BTs);  // u = 2l+2
      const float t0_ = (l == 0) ? (fa0 + Be[0]) : NEGF;     // u = 0
      float mx = fmaxf(fmaxf(to_, te_), t0_);
#pragma unroll
      for (int off = 32; off; off >>= 1) mx = fmaxf(mx, __shfl_xor(mx, off));
      float s = exp2i(to_ - mx) + exp2i(te_ - mx) +
                ((l == 0) ? exp2i(t0_ - mx) : 0.0f);
#pragma unroll
      for (int off = 32; off; off >>= 1) s += __shfl_xor(s, off);
      loss = -(mx + log2i(s)) * LN2F;
    } else {
      const float pA = __shfl(s0L, Ltg - 1);  // alpha[2*Ltg]
      const float pB = __shfl(s1L, Ltg - 1);  // alpha[2*Ltg-1]
      loss = -lse2(pA, pB) * LN2F;
    }
    if (loss > 1e20f) loss = 0.0f;
    if (!(loss <= 1e20f)) loss = 0.0f;  // NaN guard
    if (l == 0) content[n] = loss;
  }
}

// ---------------------------------------------------------------------------
// Kernel 3: final mean reduction -> scalar
// ---------------------------------------------------------------------------
__global__ __launch_bounds__(64) void k_red(
    const float* __restrict__ content, const float* __restrict__ pen,
    float* __restrict__ out) {
  const int l = threadIdx.x;
  float v = content[l] + pen[l];  // STRUCT_WEIGHT = 1.0
#pragma unroll
  for (int off = 32; off; off >>= 1) v += __shfl_down(v, off);
  if (l == 0) out[0] = v * (1.0f / NN);
}

extern "C" void kernel_launch(void* const* d_in, const int* in_sizes, int n_in,
                              void* d_out, int out_size, void* d_ws,
                              size_t ws_size, hipStream_t stream) {
  const float* log_probs = (const float*)d_in[0];  // (T,N,C) f32
  const int* targets = (const int*)d_in[1];        // (N,S) i32
  const int* input_lengths = (const int*)d_in[2];  // (N,) i32
  const int* target_lengths = (const int*)d_in[3]; // (N,) i32
  float* out = (float*)d_out;

  // workspace layout
  unsigned short* Wt16 = (unsigned short*)d_ws;      // [N*64][T] bf16 (8.4 MB)
  float* Wb = (float*)(Wt16 + (size_t)NN * 64 * TT); // [N][T] f32 (256 KB)
  int* pred = (int*)(Wb + (size_t)NN * TT);          // [N][T] i32 (256 KB)
  float* content = (float*)(pred + (size_t)NN * TT);
  float* pen = content + NN;

  k_rowpass<<<NN * (TT / 16), 256, 0, stream>>>(log_probs, targets, Wt16, Wb,
                                                pred);
  k_ctc<<<NN, 192, 0, stream>>>(Wt16, Wb, targets, input_lengths,
                                target_lengths, pred, content, pen);
  k_red<<<1, 64, 0, stream>>>(content, pen, out);
}

// Round 9
// 54.406 us; speedup vs baseline: 5.7768x; 1.0499x over previous
//
#include <hip/hip_runtime.h>
#include <hip/hip_bf16.h>
#include <cstdint>
#include <cstddef>

#define TT 1024
#define NN 64
#define CC 512
#define SS 64
#define TCH 32  // t-chunk per rowpass block
#define NEGF (-1e30f)
#define LN2F 0.6931471805599453f
#define SMALLE (-0x40000000)

__device__ __forceinline__ float exp2i(float x) { return __builtin_amdgcn_exp2f(x); }
__device__ __forceinline__ float log2i(float x) { return __builtin_amdgcn_logf(x); }

__device__ __forceinline__ float ldx(float x, int e) {
#if __has_builtin(__builtin_amdgcn_ldexpf)
  return __builtin_amdgcn_ldexpf(x, e);
#else
  return ldexpf(x, e);
#endif
}

// log-sum-exp in log2 domain (final combine only)
__device__ __forceinline__ float lse2(float x, float y) {
  float m = fmaxf(x, y);
  float d = fabsf(x - y);
  return m + log2i(1.0f + exp2i(-d));
}
__device__ __forceinline__ float lse3(float x, float y, float z) {
  float m = fmaxf(fmaxf(x, y), z);
  float s = exp2i(x - m) + exp2i(y - m) + exp2i(z - m);
  return m + log2i(s);
}

// lane l gets lane l-1's value; lane 0 gets `oldv` (DPP wave_shr:1) — HW-verified R2/R5/R7.
__device__ __forceinline__ float dpp_shr1(float x, float oldv) {
  int r = __builtin_amdgcn_update_dpp(__float_as_int(oldv), __float_as_int(x),
                                      0x138, 0xF, 0xF, false);
  return __int_as_float(r);
}
__device__ __forceinline__ int dpp_shr1_i(int x, int oldv) {
  return __builtin_amdgcn_update_dpp(oldv, x, 0x138, 0xF, 0xF, false);
}

// one u64-max DPP reduction step (old = self: uncovered lanes keep own key)
template <int CTRL>
__device__ __forceinline__ unsigned long long dpp_umax64(unsigned long long k) {
  const int lo = (int)(unsigned)k;
  const int hi = (int)(unsigned)(k >> 32);
  const int slo = __builtin_amdgcn_update_dpp(lo, lo, CTRL, 0xF, 0xF, false);
  const int shi = __builtin_amdgcn_update_dpp(hi, hi, CTRL, 0xF, 0xF, false);
  const unsigned long long o =
      ((unsigned long long)(unsigned)shi << 32) | (unsigned)slo;
  return o > k ? o : k;
}

// argmax key: monotone for log-softmax values (all < 0). Low bits: 511-idx
// so max picks the FIRST index on exact ties.  [HW-verified R7]
__device__ __forceinline__ unsigned long long akey(float v, int idx) {
  return ((unsigned long long)(~__float_as_uint(v)) << 32) |
         (unsigned)(511 - idx);
}
__device__ __forceinline__ unsigned long long umax64(unsigned long long a,
                                                     unsigned long long b) {
  return a > b ? a : b;
}

// f32 -> bf16 RNE (inputs are finite positive probs)
__device__ __forceinline__ unsigned bf16rne(float f) {
  unsigned u = __float_as_uint(f);
  return (u + 0x7FFFu + ((u >> 16) & 1u)) >> 16;
}

// bf16 halves of a u32 -> f32
#define BF_LO(r) __uint_as_float((r) << 16)
#define BF_HI(r) __uint_as_float((r) & 0xFFFF0000u)

// ---------------------------------------------------------------------------
// Kernel 1: fused row pass. Block = one n x 32 consecutive t, 4 waves x 8
// rows. Per row: DPP-u64 argmax -> pred; LINEAR target weights bf16,
// transposed (full 64B line per lane-strip per block): Wt16[(n*64+s)][t];
// blank weight f32: Wb[n][t]. Block 0 also zeroes out[0] for ctc's atomics.
// ---------------------------------------------------------------------------
__global__ __launch_bounds__(256) void k_rowpass(
    const float* __restrict__ lp, const int* __restrict__ targets,
    unsigned short* __restrict__ Wt16, float* __restrict__ Wb,
    int* __restrict__ pred, float* __restrict__ out) {
  __shared__ float rows[4][CC];
  __shared__ float Gs[TCH][65];
  __shared__ float Gsb[TCH];
  const int tid = threadIdx.x;
  const int wid = tid >> 6;
  const int l = tid & 63;
  const int n = blockIdx.x & 63;
  const int tc = blockIdx.x >> 6;  // t-chunk of 32

  if (blockIdx.x == 0 && tid == 0) out[0] = 0.0f;

  const int tgt = targets[n * SS + l];

  for (int i = 0; i < 8; ++i) {
    const int tl = wid * 8 + i;  // local t in [0,32)
    const int t = tc * TCH + tl;
    const float* row = lp + ((size_t)t * NN + n) * CC;
    const float4 v0 = ((const float4*)row)[l];
    const float4 v1 = ((const float4*)row)[l + 64];
    ((float4*)rows[wid])[l] = v0;
    ((float4*)rows[wid])[l + 64] = v1;

    // argmax: packed u64 keys, local tree + DPP wave reduce (lane 63 valid)
    const unsigned long long ka =
        umax64(akey(v0.x, 4 * l), akey(v0.y, 4 * l + 1));
    const unsigned long long kb =
        umax64(akey(v0.z, 4 * l + 2), akey(v0.w, 4 * l + 3));
    const unsigned long long kc =
        umax64(akey(v1.x, 256 + 4 * l), akey(v1.y, 256 + 4 * l + 1));
    const unsigned long long kd =
        umax64(akey(v1.z, 256 + 4 * l + 2), akey(v1.w, 256 + 4 * l + 3));
    unsigned long long k = umax64(umax64(ka, kb), umax64(kc, kd));
    k = dpp_umax64<0x111>(k);  // row_shr:1
    k = dpp_umax64<0x112>(k);  // row_shr:2
    k = dpp_umax64<0x114>(k);  // row_shr:4
    k = dpp_umax64<0x118>(k);  // row_shr:8
    k = dpp_umax64<0x142>(k);  // row_bcast:15
    k = dpp_umax64<0x143>(k);  // row_bcast:31

    const float gv = rows[wid][tgt];
    Gs[tl][l] = __expf(gv);  // linear p(tgt)
    if (l == 63) pred[n * TT + t] = 511 - (int)(unsigned)k;
    if (l == 0) Gsb[tl] = __expf(v0.x);  // linear p(blank)
  }
  __syncthreads();

  // transpose write: thread (l, q) packs 8 t's (bf16, 16B) for strip l;
  // the 4 q-threads of one l cover 64 consecutive bytes -> full line.
  const int q = tid >> 6;
  uint4 wv;
  wv.x = bf16rne(Gs[q * 8 + 0][l]) | (bf16rne(Gs[q * 8 + 1][l]) << 16);
  wv.y = bf16rne(Gs[q * 8 + 2][l]) | (bf16rne(Gs[q * 8 + 3][l]) << 16);
  wv.z = bf16rne(Gs[q * 8 + 4][l]) | (bf16rne(Gs[q * 8 + 5][l]) << 16);
  wv.w = bf16rne(Gs[q * 8 + 6][l]) | (bf16rne(Gs[q * 8 + 7][l]) << 16);
  *(uint4*)(Wt16 + (size_t)(n * 64 + l) * TT + tc * TCH + q * 8) = wv;
  if (tid < TCH) Wb[(size_t)n * TT + tc * TCH + tid] = Gsb[tid];
}

// ---------------------------------------------------------------------------
// Kernel 2: CTC fwd/bwd in LINEAR domain with per-lane exponent frames.
// FSTEP/BSTEP/RENORM are the R7-VERIFIED forms VERBATIM — in particular
// us = ldx(uu, dEnb): uu==0 short-circuits huge dEnb at the backward
// boundary (empty-neighbor frame gap reaches +3000; ldx(wt,dEnb) = inf
// there, which is what broke R6/R8 via 0*inf=NaN).
// + fused structural penalty (wave 2) + fused mean via atomicAdd.
// ---------------------------------------------------------------------------
__global__ __launch_bounds__(192) void k_ctc(
    const unsigned short* __restrict__ Wt16, const float* __restrict__ Wb,
    const int* __restrict__ targets, const int* __restrict__ ilen,
    const int* __restrict__ tlen, const int* __restrict__ pred,
    float* __restrict__ out) {
  __shared__ float Bo[64], Be[64], BTs, penv;
  __shared__ int ts[SS];
  const int n = blockIdx.x;
  const int tid = threadIdx.x;
  const int wid = tid >> 6;
  const int l = tid & 63;

  const int Lm1 = __builtin_amdgcn_readfirstlane(ilen[n]) - 1;
  const int Ltg = __builtin_amdgcn_readfirstlane(tlen[n]);

  float fe0 = NEGF, fe1 = NEGF, fa0 = NEGF;
  float s0L = NEGF, s1L = NEGF;  // snapshot (Lm1 < 512), log2

  if (wid == 0) {
    // ---------------- forward wave: t = 0 .. 511 ----------------
    const int tgt = targets[n * SS + l];
    const int tprev = __shfl_up(tgt, 1);
    const float skipf = ((l == 0) || (tgt != tprev)) ? 1.0f : 0.0f;
    const uint2* bt = (const uint2*)(Wt16 + (size_t)(n * 64 + l) * TT);
    const float4* bb = (const float4*)(Wb + (size_t)n * TT);
    uint2 ring[8];
    float4 ringb[8];
#pragma unroll
    for (int i = 0; i < 8; ++i) {
      ring[i] = bt[i];
      ringb[i] = bb[i];
    }

    float Q0 = 0.0f, Q1 = 0.0f, Qa = 1.0f;
    int E = 0, Ea = 0, dEnb = 0, dEa = 0;
    float sQ0 = 0.0f, sQ1 = 0.0f;
    int sE = 0;

#define FSTEP(WTv, WBv)                              \
    {                                                \
      const float a0f = ldx(Qa, dEa);                \
      const float up0 = dpp_shr1(Q0, a0f);           \
      const float up1 = dpp_shr1(Q1, 0.0f);          \
      const float uu = fmaf(skipf, up1, up0);        \
      const float us = ldx(uu, dEnb);                \
      const float n1 = (Q1 + us) * (WTv);            \
      const float n0 = (Q0 + Q1) * (WBv);            \
      Qa *= (WBv);                                   \
      Q0 = n0;                                       \
      Q1 = n1;                                       \
    }
#define FRENORM                                               \
    {                                                         \
      const float mq = fmaxf(Q0, Q1);                         \
      const int eo = (mq > 0.0f)                              \
          ? (E + (((__float_as_int(mq) >> 23) & 255) - 127))  \
          : SMALLE;                                           \
      const int en = dpp_shr1_i(eo, SMALLE);                  \
      int En = (eo > en) ? eo : en;                           \
      if (En == SMALLE) En = E;                               \
      const int sh = E - En;                                  \
      Q0 = ldx(Q0, sh);                                       \
      Q1 = ldx(Q1, sh);                                       \
      E = En;                                                 \
      const int Eup = dpp_shr1_i(E, E);                       \
      dEnb = Eup - E;                                         \
      const int exa = ((__float_as_int(Qa) >> 23) & 255) - 127; \
      Ea += exa;                                              \
      Qa = ldx(Qa, -exa);                                     \
      dEa = Ea - E;                                           \
    }

    for (int g = 0; g < 16; ++g) {
#pragma unroll
      for (int ci = 0; ci < 8; ++ci) {
        const int c = g * 8 + ci;
        const uint2 wt4 = ring[ci];
        const float4 wb4 = ringb[ci];
        ring[ci] = bt[c + 8];  // overshoot stays inside d_ws
        ringb[ci] = bb[c + 8];
        if (__builtin_expect((unsigned)(Lm1 - c * 4) < 4u, 0)) {
          FSTEP(BF_LO(wt4.x), wb4.x);
          if (c * 4 + 0 == Lm1) { sQ0 = Q0; sQ1 = Q1; sE = E; }
          FSTEP(BF_HI(wt4.x), wb4.y);
          if (c * 4 + 1 == Lm1) { sQ0 = Q0; sQ1 = Q1; sE = E; }
          FSTEP(BF_LO(wt4.y), wb4.z);
          if (c * 4 + 2 == Lm1) { sQ0 = Q0; sQ1 = Q1; sE = E; }
          FSTEP(BF_HI(wt4.y), wb4.w);
          if (c * 4 + 3 == Lm1) { sQ0 = Q0; sQ1 = Q1; sE = E; }
        } else {
          FSTEP(BF_LO(wt4.x), wb4.x);
          FSTEP(BF_HI(wt4.x), wb4.y);
          FSTEP(BF_LO(wt4.y), wb4.z);
          FSTEP(BF_HI(wt4.y), wb4.w);
        }
        FRENORM;
      }
    }
#undef FSTEP
#undef FRENORM
    const float fE = (float)E;
    fe0 = (Q0 > 0.0f) ? (log2i(Q0) + fE) : NEGF;
    fe1 = (Q1 > 0.0f) ? (log2i(Q1) + fE) : NEGF;
    fa0 = (Qa > 0.0f) ? (log2i(Qa) + (float)Ea) : NEGF;
    s0L = (sQ0 > 0.0f) ? (log2i(sQ0) + (float)sE) : NEGF;
    s1L = (sQ1 > 0.0f) ? (log2i(sQ1) + (float)sE) : NEGF;
  } else if (wid == 1) {
    // ---------------- backward wave: t = 1023 .. 512 ----------------
    const int m = 63 - l;
    const int tm = targets[n * SS + m];
    const int tmp = __shfl_up(tm, 1);  // lane l-1 holds m+1
    const float skipbf = ((l > 0) && (tm != tmp)) ? 1.0f : 0.0f;
    const uint2* bt = (const uint2*)(Wt16 + (size_t)(n * 64 + m) * TT);
    const float4* bb = (const float4*)(Wb + (size_t)n * TT);
    uint2 ring[8];
    float4 ringb[8];
#pragma unroll
    for (int i = 0; i < 8; ++i) {
      ring[i] = bt[255 - i];
      ringb[i] = bb[255 - i];
    }

    float Qd0 = 0.0f, Qd1 = 0.0f, QaT = 0.0f;
    int Eb = 0, EaT = 0, dEnb = 0, dEa = 0;

#define BSTEP(WTv, WBv)                              \
    {                                                \
      const float aTf = ldx(QaT, dEa);               \
      const float nd0 = dpp_shr1(Qd0, aTf);          \
      const float nd1 = dpp_shr1(Qd1, 0.0f);         \
      const float uu = fmaf(skipbf, nd1, nd0);       \
      const float us = ldx(uu, dEnb);                \
      const float n1 = (Qd1 + us) * (WTv);           \
      const float n0 = (Qd0 + Qd1) * (WBv);          \
      QaT *= (WBv);                                  \
      Qd0 = n0;                                      \
      Qd1 = n1;                                      \
    }
#define BINIT(WTv, WBv)                              \
    {                                                \
      Qd0 = (m == Ltg) ? (WBv) : 0.0f;               \
      Qd1 = (m == Ltg - 1) ? (WTv) : 0.0f;           \
      QaT = (Ltg == 64) ? (WBv) : 0.0f;              \
      Eb = 0; EaT = 0; dEnb = 0; dEa = 0;            \
    }
#define BRENORM                                               \
    {                                                         \
      const float mq = fmaxf(Qd0, Qd1);                       \
      const int eo = (mq > 0.0f)                              \
          ? (Eb + (((__float_as_int(mq) >> 23) & 255) - 127)) \
          : SMALLE;                                           \
      const int en = dpp_shr1_i(eo, SMALLE);                  \
      int En = (eo > en) ? eo : en;                           \
      if (En == SMALLE) En = Eb;                              \
      const int sh = Eb - En;                                 \
      Qd0 = ldx(Qd0, sh);                                     \
      Qd1 = ldx(Qd1, sh);                                     \
      Eb = En;                                                \
      const int Eup = dpp_shr1_i(Eb, Eb);                     \
      dEnb = Eup - Eb;                                        \
      if (QaT > 0.0f) {                                       \
        const int exa = ((__float_as_int(QaT) >> 23) & 255) - 127; \
        EaT += exa;                                           \
        QaT = ldx(QaT, -exa);                                 \
      }                                                       \
      dEa = EaT - Eb;                                         \
    }

    for (int g = 0; g < 16; ++g) {
#pragma unroll
      for (int ci = 0; ci < 8; ++ci) {
        const int cs = g * 8 + ci;
        const uint2 wt4 = ring[ci];
        const float4 wb4 = ringb[ci];
        ring[ci] = bt[255 - cs - 8];
        ringb[ci] = bb[255 - cs - 8];
        const int thi = 1023 - 4 * cs;
        if (__builtin_expect((unsigned)(thi - Lm1) < 4u, 0)) {
          if (thi - 0 == Lm1) BINIT(BF_HI(wt4.y), wb4.w) else BSTEP(BF_HI(wt4.y), wb4.w);
          if (thi - 1 == Lm1) BINIT(BF_LO(wt4.y), wb4.z) else BSTEP(BF_LO(wt4.y), wb4.z);
          if (thi - 2 == Lm1) BINIT(BF_HI(wt4.x), wb4.y) else BSTEP(BF_HI(wt4.x), wb4.y);
          if (thi - 3 == Lm1) BINIT(BF_LO(wt4.x), wb4.x) else BSTEP(BF_LO(wt4.x), wb4.x);
        } else {
          BSTEP(BF_HI(wt4.y), wb4.w);
          BSTEP(BF_LO(wt4.y), wb4.z);
          BSTEP(BF_HI(wt4.x), wb4.y);
          BSTEP(BF_LO(wt4.x), wb4.x);
        }
        BRENORM;
      }
    }
#undef BSTEP
#undef BINIT
#undef BRENORM

    // convert to log2; boundary combine step (R4-verified shape)
    const float fEb = (float)Eb;
    const float d0L = (Qd0 > 0.0f) ? (log2i(Qd0) + fEb) : NEGF;
    const float d1L = (Qd1 > 0.0f) ? (log2i(Qd1) + fEb) : NEGF;
    const float aTL = (QaT > 0.0f) ? (log2i(QaT) + (float)EaT) : NEGF;
    const float nd0 = dpp_shr1(d0L, aTL);
    const float nd1 = dpp_shr1(d1L, NEGF);
    const float skz = ((l > 0) && (tm != tmp)) ? nd1 : NEGF;
    Bo[m] = lse3(d1L, nd0, skz);
    Be[m] = lse2(d0L, d1L);
    if (l == 0) BTs = aTL;
  } else {
    // ---------------- penalty wave ----------------
    const int tv = targets[n * SS + l];
    const bool tf = (l < Ltg) && (tv >= 1) && (tv <= 8);
    const unsigned long long tmk = __ballot(tf);
    const int tcnt = __popcll(tmk);
    if (tf) ts[__popcll(tmk & ((1ull << l) - 1ull))] = tv;

    const int L_in = Lm1 + 1;
    int mism = 0;
    int prevc = -1;
    int base = 0;
#pragma unroll 4
    for (int c = 0; c < TT / 64; ++c) {
      const int t = c * 64 + l;
      int p = pred[n * TT + t];
      if (t >= L_in) p = 0;
      int pp = __shfl_up(p, 1);
      if (l == 0) pp = prevc;
      const bool keep = (p != pp) && (p >= 1) && (p <= 8);
      const unsigned long long mk = __ballot(keep);
      const int pos = base + __popcll(mk & ((1ull << l) - 1ull));
      if (keep && (pos >= tcnt || ts[pos] != p)) mism = 1;
      base += __popcll(mk);
      prevc = __shfl(p, 63);
    }
    if (base != tcnt) mism = 1;
    if (__any(mism)) mism = 1;
    if (l == 0) penv = mism ? 1.0f : 0.0f;
  }

  __syncthreads();

  if (wid == 0) {
    float loss;
    if (Lm1 >= 512) {
      const float to_ = fe1 + Bo[l];                         // u = 2l+1
      const float te_ = fe0 + ((l < 63) ? Be[l + 1] : BTs);  // u = 2l+2
      const float t0_ = (l == 0) ? (fa0 + Be[0]) : NEGF;     // u = 0
      float mx = fmaxf(fmaxf(to_, te_), t0_);
#pragma unroll
      for (int off = 32; off; off >>= 1) mx = fmaxf(mx, __shfl_xor(mx, off));
      float s = exp2i(to_ - mx) + exp2i(te_ - mx) +
                ((l == 0) ? exp2i(t0_ - mx) : 0.0f);
#pragma unroll
      for (int off = 32; off; off >>= 1) s += __shfl_xor(s, off);
      loss = -(mx + log2i(s)) * LN2F;
    } else {
      const float pA = __shfl(s0L, Ltg - 1);  // alpha[2*Ltg]
      const float pB = __shfl(s1L, Ltg - 1);  // alpha[2*Ltg-1]
      loss = -lse2(pA, pB) * LN2F;
    }
    if (loss > 1e20f) loss = 0.0f;
    if (!(loss <= 1e20f)) loss = 0.0f;  // NaN guard
    if (l == 0) atomicAdd(out, (loss + penv) * (1.0f / NN));
  }
}

extern "C" void kernel_launch(void* const* d_in, const int* in_sizes, int n_in,
                              void* d_out, int out_size, void* d_ws,
                              size_t ws_size, hipStream_t stream) {
  const float* log_probs = (const float*)d_in[0];  // (T,N,C) f32
  const int* targets = (const int*)d_in[1];        // (N,S) i32
  const int* input_lengths = (const int*)d_in[2];  // (N,) i32
  const int* target_lengths = (const int*)d_in[3]; // (N,) i32
  float* out = (float*)d_out;

  // workspace layout
  unsigned short* Wt16 = (unsigned short*)d_ws;      // [N*64][T] bf16 (8.4 MB)
  float* Wb = (float*)(Wt16 + (size_t)NN * 64 * TT); // [N][T] f32 (256 KB)
  int* pred = (int*)(Wb + (size_t)NN * TT);          // [N][T] i32 (256 KB)

  k_rowpass<<<NN * (TT / TCH), 256, 0, stream>>>(log_probs, targets, Wt16, Wb,
                                                 pred, out);
  k_ctc<<<NN, 192, 0, stream>>>(Wt16, Wb, targets, input_lengths,
                                target_lengths, pred, out);
}